// Round 19
// baseline (169.810 us; speedup 1.0000x reference)
//
#include <hip/hip_runtime.h>
#include <cstddef>

// Problem constants
#define TT 2048
#define BB 2
#define CC 768
#define NH 12
#define HD 64
#define N3 2304          // 3*NH*HD
#define Y_ELEMS (BB*TT*CC)          // 3145728
#define M_ELEMS (BB*TT*TT)          // 8388608

typedef __attribute__((ext_vector_type(8))) short bf16x8;
typedef __attribute__((ext_vector_type(4))) float f32x4;

__device__ inline unsigned short f2b(float f) {
  union { float f; unsigned u; } v; v.f = f;
  unsigned r = (v.u + 0x7FFFu + ((v.u >> 16) & 1u)) >> 16;
  return (unsigned short)r;
}
__device__ inline float b2f(unsigned short u) {
  union { unsigned u; float f; } v; v.u = (unsigned)u << 16; return v.f;
}
__device__ inline unsigned short f2h(float f) {
  _Float16 h = (_Float16)f;
  return *(unsigned short*)&h;
}
__device__ inline float h2f(unsigned short u) {
  _Float16 h = *(_Float16*)&u;
  return (float)h;
}

// async global -> LDS, 16B per lane; lds dest is wave-uniform base, HW adds lane*16
__device__ inline void gload_lds16(const unsigned short* g, unsigned short* l) {
  __builtin_amdgcn_global_load_lds(
      (const __attribute__((address_space(1))) unsigned int*)g,
      (__attribute__((address_space(3))) unsigned int*)l, 16, 0, 0);
}

// ---------------------------------------------------------------------------
// FUSED prep + head-0 qk kernel (1D grid, 2368 blocks):
//   bid <   256 : fp32 GEMM q0/k0 (32x64 tile) — LONG blocks first.
//   bid <  1792 : pack x (fp32 -> bf16)
//   bid <  2224 : transpose-pack w_attn -> wbT
//   else        : transpose-pack w_proj -> wpT
// ---------------------------------------------------------------------------
__global__ __launch_bounds__(256) void prep_fused(
    const float* __restrict__ x, const float* __restrict__ w_attn,
    const float* __restrict__ w_proj, const float* __restrict__ b_attn,
    unsigned short* __restrict__ xb, unsigned short* __restrict__ wbT,
    unsigned short* __restrict__ wpT,
    float* __restrict__ q0, float* __restrict__ k0) {
  int bid = blockIdx.x;
  int tid = threadIdx.x;
  if (bid < 256) {
    __shared__ float As[16][32];
    __shared__ float Bs[16][64];
    int sec = bid >> 7;
    int mt = bid & 127;
    const float* Bw = w_attn + sec * CC;
    float* Out = sec ? k0 : q0;
    int tx = tid & 15, ty = tid >> 4;
    int m0 = mt * 32;

    int arow = tid >> 3;
    int acol2 = (tid & 7) << 1;
    int brow = tid >> 4;
    int bcol4 = (tid & 15) << 2;

    const float* Aptr = x + (size_t)(m0 + arow) * CC + acol2;
    const float* Bptr = Bw + (size_t)brow * N3 + bcol4;

    float acc[2][4] = {};
    for (int k0_ = 0; k0_ < CC; k0_ += 16) {
      float2 av = *(const float2*)(Aptr + k0_);
      float4 bv = *(const float4*)(Bptr + (size_t)k0_ * N3);
      As[acol2 + 0][arow] = av.x;
      As[acol2 + 1][arow] = av.y;
      *(float4*)&Bs[brow][bcol4] = bv;
      __syncthreads();
#pragma unroll
      for (int kk = 0; kk < 16; ++kk) {
        float2 a2 = *(const float2*)&As[kk][ty << 1];
        float4 b4 = *(const float4*)&Bs[kk][tx << 2];
        float a[2] = {a2.x, a2.y};
        float b[4] = {b4.x, b4.y, b4.z, b4.w};
#pragma unroll
        for (int ii = 0; ii < 2; ++ii)
#pragma unroll
          for (int jj = 0; jj < 4; ++jj) acc[ii][jj] += a[ii] * b[jj];
      }
      __syncthreads();
    }
    float4 bv = *(const float4*)(b_attn + sec * CC + (tx << 2));
#pragma unroll
    for (int ii = 0; ii < 2; ++ii) {
      int m = m0 + (ty << 1) + ii;
      float4 o;
      o.x = acc[ii][0] + bv.x;
      o.y = acc[ii][1] + bv.y;
      o.z = acc[ii][2] + bv.z;
      o.w = acc[ii][3] + bv.w;
      *(float4*)(Out + (size_t)m * HD + (tx << 2)) = o;
    }
    return;
  }
  if (bid < 1792) {
    size_t i = ((size_t)(bid - 256) * 256 + tid) * 8;
    float4 a = *(const float4*)(x + i);
    float4 b = *(const float4*)(x + i + 4);
    ushort4 o0, o1;
    o0.x = f2b(a.x); o0.y = f2b(a.y); o0.z = f2b(a.z); o0.w = f2b(a.w);
    o1.x = f2b(b.x); o1.y = f2b(b.y); o1.z = f2b(b.z); o1.w = f2b(b.w);
    *(ushort4*)(xb + i) = o0;
    *(ushort4*)(xb + i + 4) = o1;
    return;
  }
  const float* W;
  unsigned short* WT;
  int N, kt, nt;
  if (bid < 2224) {
    int t = bid - 1792;
    W = w_attn; WT = wbT; N = N3;
    kt = t % 12; nt = t / 12;
  } else {
    int t = bid - 2224;
    W = w_proj; WT = wpT; N = CC;
    kt = t % 12; nt = t / 12;
  }
  __shared__ float tile[64][65];
  int r = tid >> 4, c4 = (tid & 15) << 2;
#pragma unroll
  for (int rep = 0; rep < 4; ++rep) {
    int row = rep * 16 + r;
    float4 v = *(const float4*)(W + (size_t)(kt * 64 + row) * N + nt * 64 + c4);
    tile[row][c4 + 0] = v.x; tile[row][c4 + 1] = v.y;
    tile[row][c4 + 2] = v.z; tile[row][c4 + 3] = v.w;
  }
  __syncthreads();
#pragma unroll
  for (int rep = 0; rep < 4; ++rep) {
    int nrow = rep * 16 + r;
    ushort4 o;
    o.x = f2b(tile[c4 + 0][nrow]); o.y = f2b(tile[c4 + 1][nrow]);
    o.z = f2b(tile[c4 + 2][nrow]); o.w = f2b(tile[c4 + 3][nrow]);
    *(ushort4*)(WT + (size_t)(nt * 64 + nrow) * CC + kt * 64 + c4) = o;
  }
}

// ---------------------------------------------------------------------------
// FUSED QKV MFMA GEMM + head-0 scores. 1D grid, 2624 blocks:
//   bid <  576 : bf16 MFMA qkv (128x128 tile) — LONG blocks, dispatched first
//   else       : score0 (fp32 compute, fp16 store + fused column partials)
// LDS: one 34816B buffer overlaid by both paths.
// ---------------------------------------------------------------------------
__global__ __launch_bounds__(256, 3) void gemm_score_fused(
    const unsigned short* __restrict__ xb, const unsigned short* __restrict__ wbT,
    const float* __restrict__ b_attn,
    unsigned short* __restrict__ Qb, unsigned short* __restrict__ Kb,
    unsigned short* __restrict__ Vt,
    const float* __restrict__ q0, const float* __restrict__ k0,
    unsigned short* __restrict__ Sbuf16, float* __restrict__ partials) {
  __shared__ __align__(16) unsigned short smem_u[17408];  // 34816 B
  int bid = blockIdx.x;
  int tid = threadIdx.x;

  if (bid >= 576) {
    // ---------------- score0 path (fp16 S store) ----------------
    int t = bid - 576;
    int b = t >> 10;
    int rem = t & 1023;
    int it = rem >> 5, jt = rem & 31;
    int i0 = it * 64, j0 = jt * 64;
    if (jt > it) {
      if (tid < 64) partials[((size_t)(b * 32 + it)) * TT + j0 + tid] = 0.f;
      return;
    }
    float (*Qs)[64] = (float(*)[64])smem_u;                  // 16384 B
    float (*Ks)[64] = (float(*)[64])(smem_u + 8192);         // 16384 B
    int row = tid >> 2;
    int dq = (tid & 3) << 2;
    const float* qb = q0 + (size_t)((b * TT) + i0 + row) * HD;
    const float* kb = k0 + (size_t)((b * TT) + j0 + row) * HD;
#pragma unroll
    for (int rep = 0; rep < 4; ++rep) {
      int d = dq + rep * 16;
      float4 qv = *(const float4*)(qb + d);
      float4 kv = *(const float4*)(kb + d);
      Qs[d + 0][row] = qv.x; Qs[d + 1][row] = qv.y;
      Qs[d + 2][row] = qv.z; Qs[d + 3][row] = qv.w;
      Ks[d + 0][row] = kv.x; Ks[d + 1][row] = kv.y;
      Ks[d + 2][row] = kv.z; Ks[d + 3][row] = kv.w;
    }
    __syncthreads();
    int tx = tid & 15, ty = tid >> 4;
    float acc[4][4] = {};
#pragma unroll 8
    for (int kk = 0; kk < 64; ++kk) {
      float4 a4 = *(const float4*)&Qs[kk][ty << 2];
      float4 b4 = *(const float4*)&Ks[kk][tx << 2];
      float a[4] = {a4.x, a4.y, a4.z, a4.w};
      float bb[4] = {b4.x, b4.y, b4.z, b4.w};
#pragma unroll
      for (int ii = 0; ii < 4; ++ii)
#pragma unroll
        for (int jj = 0; jj < 4; ++jj) acc[ii][jj] += a[ii] * bb[jj];
    }
    float red4[4] = {0.f, 0.f, 0.f, 0.f};
#pragma unroll
    for (int ii = 0; ii < 4; ++ii) {
      int r = i0 + (ty << 2) + ii;
      int gi = (b * TT) + r;
      float ov[4];
#pragma unroll
      for (int jj = 0; jj < 4; ++jj) {
        ov[jj] = fmaxf(acc[ii][jj] * 0.125f, 0.f);
        int j = j0 + (tx << 2) + jj;
        if (j >= 1 && j < r) red4[jj] += ov[jj];
      }
      ushort4 o;
      o.x = f2h(ov[0]); o.y = f2h(ov[1]); o.z = f2h(ov[2]); o.w = f2h(ov[3]);
      *(ushort4*)(Sbuf16 + (size_t)gi * TT + j0 + (tx << 2)) = o;
    }
    __syncthreads();  // everyone done reading Qs
    *(float4*)&Qs[ty][tx << 2] = *(float4*)red4;
    __syncthreads();
    if (tid < 64) {
      float cs = 0.f;
#pragma unroll
      for (int t2 = 0; t2 < 16; ++t2) cs += Qs[t2][tid];
      partials[((size_t)(b * 32 + it)) * TT + j0 + tid] = cs;
    }
    return;
  }

  // ---------------- bf16 MFMA qkv path ----------------
  unsigned short (*Alds)[128][32] = (unsigned short(*)[128][32])smem_u;
  unsigned short (*Blds)[128][32] = (unsigned short(*)[128][32])(smem_u + 8192);
  unsigned short (*Vlds)[136]     = (unsigned short(*)[136])smem_u;

  int mt = bid & 31, nt = bid >> 5;
  int sec = nt / 6, h0 = (nt % 6) * 2;
  int wave = threadIdx.x >> 6, lane = threadIdx.x & 63;
  int lr = lane & 15, lg = lane >> 4;
  int m0 = mt * 128;
  int n0 = nt * 128;

  int srow = lane >> 2;                 // 0..15 staging row within segment
  int sslot = (lane & 3) ^ (srow & 3);  // pre-swizzled source k-slot (16B units)

#define STAGE_AB(BUF, K0)                                                       \
  {                                                                             \
    _Pragma("unroll")                                                           \
    for (int p = 0; p < 2; ++p) {                                               \
      int ar = wave * 32 + p * 16 + srow;                                       \
      gload_lds16(xb + (size_t)(m0 + ar) * CC + (K0) + (sslot << 3),            \
                  &Alds[BUF][wave * 32 + p * 16][0]);                           \
      gload_lds16(wbT + (size_t)(n0 + ar) * CC + (K0) + (sslot << 3),           \
                  &Blds[BUF][wave * 32 + p * 16][0]);                           \
    }                                                                           \
  }

  f32x4 acc[2][8];
#pragma unroll
  for (int mi = 0; mi < 2; ++mi)
#pragma unroll
    for (int nj = 0; nj < 8; ++nj) acc[mi][nj] = (f32x4){0.f, 0.f, 0.f, 0.f};

  STAGE_AB(0, 0)
  __syncthreads();

  int fslot = lg ^ (lr & 3);  // frag read slot (same involution)
  for (int kt = 0; kt < 24; ++kt) {
    int cur = kt & 1;
    if (kt < 23) STAGE_AB(cur ^ 1, (kt + 1) * 32)
    bf16x8 af[2], bf[8];
#pragma unroll
    for (int mi = 0; mi < 2; ++mi)
      af[mi] = *(const bf16x8*)&Alds[cur][wave * 32 + mi * 16 + lr][fslot << 3];
#pragma unroll
    for (int nj = 0; nj < 8; ++nj)
      bf[nj] = *(const bf16x8*)&Blds[cur][nj * 16 + lr][fslot << 3];
    __builtin_amdgcn_s_setprio(1);
#pragma unroll
    for (int nj = 0; nj < 8; ++nj)
#pragma unroll
      for (int mi = 0; mi < 2; ++mi)
        acc[mi][nj] = __builtin_amdgcn_mfma_f32_16x16x32_bf16(af[mi], bf[nj], acc[mi][nj], 0, 0, 0);
    __builtin_amdgcn_s_setprio(0);
    __syncthreads();
  }
#undef STAGE_AB

  int b = m0 >> 11;
  float bias[8];
#pragma unroll
  for (int nj = 0; nj < 8; ++nj) bias[nj] = b_attn[n0 + nj * 16 + lr];

  if (sec < 2) {
    // Q is pre-scaled by 1/8 (exact in bf16: exponent shift only)
    float qscale = (sec == 0) ? 0.125f : 1.0f;
    unsigned short* OutB = (sec == 0 ? Qb : Kb);
    int tbase = (m0 & 2047) + wave * 32 + lg * 4;
#pragma unroll
    for (int nj = 0; nj < 8; ++nj) {
      int h = h0 + (nj >> 2);
      int d = (nj & 3) * 16 + lr;
      unsigned short* Out = OutB + (size_t)(b * NH + h) * TT * HD;
#pragma unroll
      for (int mi = 0; mi < 2; ++mi)
#pragma unroll
        for (int r = 0; r < 4; ++r) {
          int t = tbase + mi * 16 + r;
          Out[(size_t)t * HD + d] = f2b((acc[mi][nj][r] + bias[nj]) * qscale);
        }
    }
  } else {
    int tl = wave * 32 + lg * 4;
#pragma unroll
    for (int mi = 0; mi < 2; ++mi)
#pragma unroll
      for (int r = 0; r < 4; ++r)
#pragma unroll
        for (int nj = 0; nj < 8; ++nj)
          Vlds[tl + mi * 16 + r][nj * 16 + lr] = f2b(acc[mi][nj][r] + bias[nj]);
    __syncthreads();
    int d = threadIdx.x & 63, tc = threadIdx.x >> 6;
    int tblk = (m0 & 2047);
#pragma unroll
    for (int hh = 0; hh < 2; ++hh) {
      unsigned short* Ov = Vt + ((size_t)(b * NH + h0 + hh) * HD + d) * TT + tblk + tc * 32;
      int c = hh * 64 + d;
#pragma unroll
      for (int i8 = 0; i8 < 4; ++i8) {
        ushort4 o0, o1;
        o0.x = Vlds[tc * 32 + i8 * 8 + 0][c]; o0.y = Vlds[tc * 32 + i8 * 8 + 1][c];
        o0.z = Vlds[tc * 32 + i8 * 8 + 2][c]; o0.w = Vlds[tc * 32 + i8 * 8 + 3][c];
        o1.x = Vlds[tc * 32 + i8 * 8 + 4][c]; o1.y = Vlds[tc * 32 + i8 * 8 + 5][c];
        o1.z = Vlds[tc * 32 + i8 * 8 + 6][c]; o1.w = Vlds[tc * 32 + i8 * 8 + 7][c];
        *(ushort4*)(Ov + i8 * 8) = o0;
        *(ushort4*)(Ov + i8 * 8 + 4) = o1;
      }
    }
  }
}

// ---------------------------------------------------------------------------
// Column-wise exclusive prefix scan over rows (64-row chunks). Reads fp16 S.
// Emits E = exp(-FF) bf16 (j-swizzled) + ffpart row sums. 8-row batching.
// Partials prefix unrolled x4 (independent load chains). EARLY EXIT for
// blocks whose whole column band lies above the diagonal.
// ---------------------------------------------------------------------------
__global__ __launch_bounds__(256) void scan_write(
    const unsigned short* __restrict__ Sbuf16, const float* __restrict__ partials,
    unsigned short* __restrict__ Eb, float* __restrict__ ffpart) {
  int jb = blockIdx.x;
  int chunk = blockIdx.y, b = blockIdx.z;
  int r0 = chunk * 64;
  if (jb * 256 >= r0 + 64) {  // entire band above diagonal: FF=0, E unread
    if (threadIdx.x < 64)
      ffpart[((size_t)(b * 8) + jb) * TT + r0 + threadIdx.x] = 0.f;
    return;
  }
  int j = jb * 256 + threadIdx.x;
  const float* pbase = partials + ((size_t)(b * 32)) * TT + j;
  float s0 = 0.f, s1 = 0.f, s2 = 0.f, s3 = 0.f;
  int c = 0;
  for (; c + 3 < chunk; c += 4) {
    s0 += pbase[(size_t)(c + 0) * TT];
    s1 += pbase[(size_t)(c + 1) * TT];
    s2 += pbase[(size_t)(c + 2) * TT];
    s3 += pbase[(size_t)(c + 3) * TT];
  }
  for (; c < chunk; ++c) s0 += pbase[(size_t)c * TT];
  float run = (s0 + s1) + (s2 + s3);
  int jswz = (j & ~63) | ((j & 15) << 2) | ((j >> 4) & 3);
  const unsigned short* base = Sbuf16 + (size_t)(b * TT + r0) * TT + j;
  unsigned short* ebase = Eb + (size_t)(b * TT + r0) * TT + jswz;
  __shared__ float wsum[4][64];
  int wv = threadIdx.x >> 6;
  for (int rb = 0; rb < 64; rb += 8) {
    float v[8];
#pragma unroll
    for (int u = 0; u < 8; ++u) {
      int r = r0 + rb + u;
      v[u] = (j >= 1 && j < r) ? h2f(base[(size_t)(rb + u) * TT]) : 0.f;
    }
#pragma unroll
    for (int u = 0; u < 8; ++u) {
      int rr = rb + u;
      ebase[(size_t)rr * TT] = f2b(__expf(-run));  // E (bf16, natural-e)
      float c1 = fminf(run, 1.f);                  // run >= 0 always
#pragma unroll
      for (int o = 1; o < 64; o <<= 1) c1 += __shfl_xor(c1, o);
      if ((threadIdx.x & 63) == 0) wsum[wv][rr] = c1;
      run += v[u];
    }
  }
  __syncthreads();
  if (threadIdx.x < 64)
    ffpart[((size_t)(b * 8) + jb) * TT + r0 + threadIdx.x] =
        wsum[0][threadIdx.x] + wsum[1][threadIdx.x] +
        wsum[2][threadIdx.x] + wsum[3][threadIdx.x];
}

// ---------------------------------------------------------------------------
// FUSED attention + M writer (1D grid, 1280 blocks):
//   bid <  768 : bf16 MFMA flash attention (R9 form + balanced g4) — LONG
//                blocks first; XCD = bid%8 serves one batch / 3 heads.
//   else       : M writer — short HBM-store blocks that backfill.
// ---------------------------------------------------------------------------
__global__ __launch_bounds__(256, 3) void attn_m_fused(
    const unsigned short* __restrict__ Qb, const unsigned short* __restrict__ Kb,
    const unsigned short* __restrict__ Vt, const unsigned short* __restrict__ Eb,
    unsigned short* __restrict__ yhb,
    const float* __restrict__ ffpart, float* __restrict__ Mout) {
  int bid = blockIdx.x;
  if (bid >= 768) {
    int idx4 = (bid - 768) * 256 + threadIdx.x;
    int stride = (gridDim.x - 768) * 256;
    for (; idx4 < M_ELEMS / 4; idx4 += stride) {
      int idx = idx4 << 2;
      int j = idx & (TT - 1);
      int i = (idx >> 11) & (TT - 1);
      int b = idx >> 22;
      const float* fp = ffpart + ((size_t)(b * 8)) * TT + j;
      float4 s = make_float4(0.f, 0.f, 0.f, 0.f);
#pragma unroll
      for (int p = 0; p < 8; ++p) {
        float4 v = *(const float4*)(fp + (size_t)p * TT);
        s.x += v.x; s.y += v.y; s.z += v.z; s.w += v.w;
      }
      float fi = (float)i;
      float4 o = make_float4(fi - s.x, fi - s.y, fi - s.z, fi - s.w);
      *(float4*)(Mout + idx) = o;
    }
    return;
  }
  int xbh = bid % 24;
  int b = (xbh >> 2) & 1;
  int h = ((xbh >> 3) << 2) | (xbh & 3);
  int yy = bid / 24;
  int g4 = (yy & 1) ? (yy >> 1) : (31 - (yy >> 1));  // balanced interleave
  int wave = threadIdx.x >> 6, lane = threadIdx.x & 63;
  int lr = lane & 15, lg = lane >> 4;
  int i0 = g4 * 64 + wave * 16;
  int bh = b * NH + h;
  const unsigned short* Qh = Qb + (size_t)bh * TT * HD;
  const unsigned short* Kh = Kb + (size_t)bh * TT * HD;
  const unsigned short* Vh = Vt + (size_t)bh * HD * TT;
  const unsigned short* Erow = Eb + ((size_t)(b * TT) + i0 + lg * 4) * TT + 4 * lr;

  __shared__ __align__(16) unsigned short Ksh[2][64][64];
  __shared__ __align__(16) unsigned short Vsh[2][64][64];
  __shared__ __align__(16) unsigned short Plds[4][16][80];

  int rowoff = lane >> 3;            // 0..7 within an 8-row staging segment
  int sslot  = (lane & 7) ^ rowoff;  // pre-swizzled source slot (16B units)

  bf16x8 qf[2];
#pragma unroll
  for (int ks = 0; ks < 2; ++ks)
    qf[ks] = *(const bf16x8*)(Qh + (size_t)(i0 + lr) * HD + ks * 32 + lg * 8);

  f32x4 acc[4];
  float lrun[4] = {0.f, 0.f, 0.f, 0.f};  // per-lane partial of softmax denom
#pragma unroll
  for (int q = 0; q < 4; ++q) acc[q] = (f32x4){0.f, 0.f, 0.f, 0.f};

#define STAGE_KV(BUF, J0)                                                      \
  {                                                                            \
    _Pragma("unroll")                                                          \
    for (int p = 0; p < 2; ++p) {                                              \
      int r0 = wave * 16 + p * 8;                                              \
      gload_lds16(Kh + (size_t)((J0) + r0 + rowoff) * HD + sslot * 8,          \
                  &Ksh[BUF][r0][0]);                                           \
      gload_lds16(Vh + (size_t)(r0 + rowoff) * TT + (J0) + sslot * 8,          \
                  &Vsh[BUF][r0][0]);                                           \
    }                                                                          \
  }

  STAGE_KV(0, 0)
  __syncthreads();

  for (int kt = 0; kt <= g4; ++kt) {
    int cur = kt & 1;
    int j0 = kt * 64;
    if (kt < g4) STAGE_KV(cur ^ 1, j0 + 64)

    // E for current tile (4 x 8B vector loads, swizzled layout)
    ushort4 ev[4];
#pragma unroll
    for (int r = 0; r < 4; ++r)
      ev[r] = *(const ushort4*)(Erow + (size_t)r * TT + j0);

    // ---- QK^T from swizzled LDS ----
    f32x4 s[4];
    __builtin_amdgcn_s_setprio(1);
#pragma unroll
    for (int nj = 0; nj < 4; ++nj) {
      int row = nj * 16 + lr;
      int sw = row & 7;
      bf16x8 k0f = *(const bf16x8*)&Ksh[cur][row][(lg ^ sw) << 3];
      bf16x8 k1f = *(const bf16x8*)&Ksh[cur][row][((4 + lg) ^ sw) << 3];
      f32x4 z = (f32x4){0.f, 0.f, 0.f, 0.f};
      z = __builtin_amdgcn_mfma_f32_16x16x32_bf16(qf[0], k0f, z, 0, 0, 0);
      s[nj] = __builtin_amdgcn_mfma_f32_16x16x32_bf16(qf[1], k1f, z, 0, 0, 0);
    }
    __builtin_amdgcn_s_setprio(0);

    // ---- causal mask (diagonal tile only) ----
    int ibase = i0 + lg * 4;
    if (kt == g4) {
#pragma unroll
      for (int nj = 0; nj < 4; ++nj)
#pragma unroll
        for (int r = 0; r < 4; ++r)
          if (j0 + nj * 16 + lr > ibase + r) s[nj][r] = -1e30f;
    }

    // ---- P = E * exp(s); per-lane partial l; stash bf16 P in LDS ----
#pragma unroll
    for (int r = 0; r < 4; ++r) {
      float p0 = b2f(ev[r].x) * __expf(s[0][r]);
      float p1 = b2f(ev[r].y) * __expf(s[1][r]);
      float p2 = b2f(ev[r].z) * __expf(s[2][r]);
      float p3 = b2f(ev[r].w) * __expf(s[3][r]);
      lrun[r] += (p0 + p1) + (p2 + p3);
      Plds[wave][lg * 4 + r][0 * 16 + lr] = f2b(p0);
      Plds[wave][lg * 4 + r][1 * 16 + lr] = f2b(p1);
      Plds[wave][lg * 4 + r][2 * 16 + lr] = f2b(p2);
      Plds[wave][lg * 4 + r][3 * 16 + lr] = f2b(p3);
    }

    // ---- PV from swizzled LDS ----
    bf16x8 pa0 = *(const bf16x8*)&Plds[wave][lr][lg * 8];
    bf16x8 pa1 = *(const bf16x8*)&Plds[wave][lr][32 + lg * 8];
    __builtin_amdgcn_s_setprio(1);
#pragma unroll
    for (int nd = 0; nd < 4; ++nd) {
      int row = nd * 16 + lr;
      int sw = row & 7;
      bf16x8 v0f = *(const bf16x8*)&Vsh[cur][row][(lg ^ sw) << 3];
      bf16x8 v1f = *(const bf16x8*)&Vsh[cur][row][((4 + lg) ^ sw) << 3];
      acc[nd] = __builtin_amdgcn_mfma_f32_16x16x32_bf16(pa0, v0f, acc[nd], 0, 0, 0);
      acc[nd] = __builtin_amdgcn_mfma_f32_16x16x32_bf16(pa1, v1f, acc[nd], 0, 0, 0);
    }
    __builtin_amdgcn_s_setprio(0);

    __syncthreads();
  }
#undef STAGE_KV

  // ---- epilogue: one l-reduction across the 16 lr lanes, then store ----
#pragma unroll
  for (int r = 0; r < 4; ++r) {
    lrun[r] += __shfl_xor(lrun[r], 1);
    lrun[r] += __shfl_xor(lrun[r], 2);
    lrun[r] += __shfl_xor(lrun[r], 4);
    lrun[r] += __shfl_xor(lrun[r], 8);
    float inv = 1.f / lrun[r];
    int ig = i0 + lg * 4 + r;
    unsigned short* ob = yhb + (size_t)(b * TT + ig) * CC + h * HD;
#pragma unroll
    for (int nd = 0; nd < 4; ++nd)
      ob[nd * 16 + lr] = f2b(acc[nd][r] * inv);
  }
}

// ---------------------------------------------------------------------------
// proj GEMM: y = yhb @ wpT^T + b_proj (128x128 MFMA tile). Grid (32, 6).
// ---------------------------------------------------------------------------
__global__ __launch_bounds__(256, 3) void gemm_proj_bf16(
    const unsigned short* __restrict__ yhb, const unsigned short* __restrict__ wpT,
    const float* __restrict__ b_proj, float* __restrict__ y) {
  __shared__ __align__(16) unsigned short Alds[2][128][32];
  __shared__ __align__(16) unsigned short Blds[2][128][32];
  int mt = blockIdx.x, nt = blockIdx.y;
  int wave = threadIdx.x >> 6, lane = threadIdx.x & 63;
  int lr = lane & 15, lg = lane >> 4;
  int m0 = mt * 128;
  int n0 = nt * 128;

  int srow = lane >> 2;
  int sslot = (lane & 3) ^ (srow & 3);

#define STAGE_AB(BUF, K0)                                                       \
  {                                                                             \
    _Pragma("unroll")                                                           \
    for (int p = 0; p < 2; ++p) {                                               \
      int ar = wave * 32 + p * 16 + srow;                                       \
      gload_lds16(yhb + (size_t)(m0 + ar) * CC + (K0) + (sslot << 3),           \
                  &Alds[BUF][wave * 32 + p * 16][0]);                           \
      gload_lds16(wpT + (size_t)(n0 + ar) * CC + (K0) + (sslot << 3),           \
                  &Blds[BUF][wave * 32 + p * 16][0]);                           \
    }                                                                           \
  }

  f32x4 acc[2][8];
#pragma unroll
  for (int mi = 0; mi < 2; ++mi)
#pragma unroll
    for (int nj = 0; nj < 8; ++nj) acc[mi][nj] = (f32x4){0.f, 0.f, 0.f, 0.f};

  STAGE_AB(0, 0)
  __syncthreads();

  int fslot = lg ^ (lr & 3);
  for (int kt = 0; kt < 24; ++kt) {
    int cur = kt & 1;
    if (kt < 23) STAGE_AB(cur ^ 1, (kt + 1) * 32)
    bf16x8 af[2], bf[8];
#pragma unroll
    for (int mi = 0; mi < 2; ++mi)
      af[mi] = *(const bf16x8*)&Alds[cur][wave * 32 + mi * 16 + lr][fslot << 3];
#pragma unroll
    for (int nj = 0; nj < 8; ++nj)
      bf[nj] = *(const bf16x8*)&Blds[cur][nj * 16 + lr][fslot << 3];
    __builtin_amdgcn_s_setprio(1);
#pragma unroll
    for (int nj = 0; nj < 8; ++nj)
#pragma unroll
      for (int mi = 0; mi < 2; ++mi)
        acc[mi][nj] = __builtin_amdgcn_mfma_f32_16x16x32_bf16(af[mi], bf[nj], acc[mi][nj], 0, 0, 0);
    __builtin_amdgcn_s_setprio(0);
    __syncthreads();
  }
#undef STAGE_AB

  float bias[8];
#pragma unroll
  for (int nj = 0; nj < 8; ++nj) bias[nj] = b_proj[n0 + nj * 16 + lr];
#pragma unroll
  for (int mi = 0; mi < 2; ++mi)
#pragma unroll
    for (int r = 0; r < 4; ++r) {
      int m = m0 + wave * 32 + mi * 16 + lg * 4 + r;
#pragma unroll
      for (int nj = 0; nj < 8; ++nj)
        y[(size_t)m * CC + n0 + nj * 16 + lr] = acc[mi][nj][r] + bias[nj];
    }
}

// ---------------------------------------------------------------------------
extern "C" void kernel_launch(void* const* d_in, const int* in_sizes, int n_in,
                              void* d_out, int out_size, void* d_ws, size_t ws_size,
                              hipStream_t stream) {
  const float* x      = (const float*)d_in[0];
  const float* w_attn = (const float*)d_in[1];
  const float* b_attn = (const float*)d_in[2];
  const float* w_proj = (const float*)d_in[3];
  const float* b_proj = (const float*)d_in[4];

  float* y    = (float*)d_out;          // [B,T,C]
  float* Mreg = y + Y_ELEMS;            // [B,T,T]: S16 (scratch) -> M (final)
  unsigned short* Sbuf16 = (unsigned short*)Mreg;  // fp16 S occupies front half

  float* ws = (float*)d_ws;
  float* q0       = ws;                               // B*T*64
  float* k0       = q0 + (size_t)BB * TT * HD;
  float* partials = k0 + (size_t)BB * TT * HD;        // B*32*T
  float* ffpart   = partials + (size_t)BB * 32 * TT;  // B*8*T
  unsigned short* xb  = (unsigned short*)(ffpart + (size_t)BB * 8 * TT);  // B*T*C
  unsigned short* wbT = xb + (size_t)Y_ELEMS;                 // 2304*768
  unsigned short* wpT = wbT + (size_t)N3 * CC;                // 768*768
  unsigned short* Qb  = wpT + (size_t)CC * CC;                // B*NH*T*HD
  unsigned short* Kb  = Qb + (size_t)BB * NH * TT * HD;
  unsigned short* Vt  = Kb + (size_t)BB * NH * TT * HD;
  unsigned short* yhb = Vt + (size_t)BB * NH * TT * HD;       // B*T*C
  unsigned short* Eb  = yhb + (size_t)Y_ELEMS;                // B*T*T bf16 (16.8MB)
  // total ws usage ~= 46 MB

  // 1. fused prep: qk0 (long blocks first) + packs + weight transposes
  prep_fused<<<2368, 256, 0, stream>>>(x, w_attn, w_proj, b_attn,
                                       xb, wbT, wpT, q0, k0);
  // 2. fused QKV MFMA GEMM (576 long blocks first) + score0 (fp16 S store)
  gemm_score_fused<<<2624, 256, 0, stream>>>(
      xb, wbT, b_attn, Qb, Kb, Vt, q0, k0, Sbuf16, partials);
  // 3. scan: E = exp(-FF) bf16 (jswz) + ffpart row sums (fp16 S reads)
  scan_write<<<dim3(8, 32, BB), 256, 0, stream>>>(Sbuf16, partials, Eb, ffpart);
  // 4. fused attention (768 long blocks first) + M writer (backfill stores)
  attn_m_fused<<<1280, 256, 0, stream>>>(Qb, Kb, Vt, Eb, yhb, ffpart, Mreg);
  // 5. proj GEMM (128x128)
  gemm_proj_bf16<<<dim3(32, 6), 256, 0, stream>>>(yhb, wpT, b_proj, y);
}

// Round 20
// 155.790 us; speedup vs baseline: 1.0900x; 1.0900x over previous
//
#include <hip/hip_runtime.h>
#include <cstddef>

// Problem constants
#define TT 2048
#define BB 2
#define CC 768
#define NH 12
#define HD 64
#define N3 2304          // 3*NH*HD
#define Y_ELEMS (BB*TT*CC)          // 3145728
#define M_ELEMS (BB*TT*TT)          // 8388608

typedef __attribute__((ext_vector_type(8))) short bf16x8;
typedef __attribute__((ext_vector_type(4))) float f32x4;

__device__ inline unsigned short f2b(float f) {
  union { float f; unsigned u; } v; v.f = f;
  unsigned r = (v.u + 0x7FFFu + ((v.u >> 16) & 1u)) >> 16;
  return (unsigned short)r;
}
__device__ inline float b2f(unsigned short u) {
  union { unsigned u; float f; } v; v.u = (unsigned)u << 16; return v.f;
}

// async global -> LDS, 16B per lane; lds dest is wave-uniform base, HW adds lane*16
__device__ inline void gload_lds16(const unsigned short* g, unsigned short* l) {
  __builtin_amdgcn_global_load_lds(
      (const __attribute__((address_space(1))) unsigned int*)g,
      (__attribute__((address_space(3))) unsigned int*)l, 16, 0, 0);
}

// ---------------------------------------------------------------------------
// FUSED prep + head-0 qk kernel (1D grid, 2368 blocks):
//   bid <   256 : fp32 GEMM q0/k0 (32x64 tile) — LONG blocks first.
//   bid <  1792 : pack x (fp32 -> bf16)
//   bid <  2224 : transpose-pack w_attn -> wbT
//   else        : transpose-pack w_proj -> wpT
// ---------------------------------------------------------------------------
__global__ __launch_bounds__(256) void prep_fused(
    const float* __restrict__ x, const float* __restrict__ w_attn,
    const float* __restrict__ w_proj, const float* __restrict__ b_attn,
    unsigned short* __restrict__ xb, unsigned short* __restrict__ wbT,
    unsigned short* __restrict__ wpT,
    float* __restrict__ q0, float* __restrict__ k0) {
  int bid = blockIdx.x;
  int tid = threadIdx.x;
  if (bid < 256) {
    __shared__ float As[16][32];
    __shared__ float Bs[16][64];
    int sec = bid >> 7;
    int mt = bid & 127;
    const float* Bw = w_attn + sec * CC;
    float* Out = sec ? k0 : q0;
    int tx = tid & 15, ty = tid >> 4;
    int m0 = mt * 32;

    int arow = tid >> 3;
    int acol2 = (tid & 7) << 1;
    int brow = tid >> 4;
    int bcol4 = (tid & 15) << 2;

    const float* Aptr = x + (size_t)(m0 + arow) * CC + acol2;
    const float* Bptr = Bw + (size_t)brow * N3 + bcol4;

    float acc[2][4] = {};
    for (int k0_ = 0; k0_ < CC; k0_ += 16) {
      float2 av = *(const float2*)(Aptr + k0_);
      float4 bv = *(const float4*)(Bptr + (size_t)k0_ * N3);
      As[acol2 + 0][arow] = av.x;
      As[acol2 + 1][arow] = av.y;
      *(float4*)&Bs[brow][bcol4] = bv;
      __syncthreads();
#pragma unroll
      for (int kk = 0; kk < 16; ++kk) {
        float2 a2 = *(const float2*)&As[kk][ty << 1];
        float4 b4 = *(const float4*)&Bs[kk][tx << 2];
        float a[2] = {a2.x, a2.y};
        float b[4] = {b4.x, b4.y, b4.z, b4.w};
#pragma unroll
        for (int ii = 0; ii < 2; ++ii)
#pragma unroll
          for (int jj = 0; jj < 4; ++jj) acc[ii][jj] += a[ii] * b[jj];
      }
      __syncthreads();
    }
    float4 bv = *(const float4*)(b_attn + sec * CC + (tx << 2));
#pragma unroll
    for (int ii = 0; ii < 2; ++ii) {
      int m = m0 + (ty << 1) + ii;
      float4 o;
      o.x = acc[ii][0] + bv.x;
      o.y = acc[ii][1] + bv.y;
      o.z = acc[ii][2] + bv.z;
      o.w = acc[ii][3] + bv.w;
      *(float4*)(Out + (size_t)m * HD + (tx << 2)) = o;
    }
    return;
  }
  if (bid < 1792) {
    size_t i = ((size_t)(bid - 256) * 256 + tid) * 8;
    float4 a = *(const float4*)(x + i);
    float4 b = *(const float4*)(x + i + 4);
    ushort4 o0, o1;
    o0.x = f2b(a.x); o0.y = f2b(a.y); o0.z = f2b(a.z); o0.w = f2b(a.w);
    o1.x = f2b(b.x); o1.y = f2b(b.y); o1.z = f2b(b.z); o1.w = f2b(b.w);
    *(ushort4*)(xb + i) = o0;
    *(ushort4*)(xb + i + 4) = o1;
    return;
  }
  const float* W;
  unsigned short* WT;
  int N, kt, nt;
  if (bid < 2224) {
    int t = bid - 1792;
    W = w_attn; WT = wbT; N = N3;
    kt = t % 12; nt = t / 12;
  } else {
    int t = bid - 2224;
    W = w_proj; WT = wpT; N = CC;
    kt = t % 12; nt = t / 12;
  }
  __shared__ float tile[64][65];
  int r = tid >> 4, c4 = (tid & 15) << 2;
#pragma unroll
  for (int rep = 0; rep < 4; ++rep) {
    int row = rep * 16 + r;
    float4 v = *(const float4*)(W + (size_t)(kt * 64 + row) * N + nt * 64 + c4);
    tile[row][c4 + 0] = v.x; tile[row][c4 + 1] = v.y;
    tile[row][c4 + 2] = v.z; tile[row][c4 + 3] = v.w;
  }
  __syncthreads();
#pragma unroll
  for (int rep = 0; rep < 4; ++rep) {
    int nrow = rep * 16 + r;
    ushort4 o;
    o.x = f2b(tile[c4 + 0][nrow]); o.y = f2b(tile[c4 + 1][nrow]);
    o.z = f2b(tile[c4 + 2][nrow]); o.w = f2b(tile[c4 + 3][nrow]);
    *(ushort4*)(WT + (size_t)(nt * 64 + nrow) * CC + kt * 64 + c4) = o;
  }
}

// ---------------------------------------------------------------------------
// FUSED QKV MFMA GEMM + head-0 scores. 1D grid, 2624 blocks:
//   bid <  576 : bf16 MFMA qkv (128x128 tile) — LONG blocks, dispatched first
//   else       : score0 (fp32 64x64 tile + fused column partials) — short
//                blocks that backfill CUs as gemm blocks retire.
// LDS: one 34816B buffer overlaid by both paths.
// ---------------------------------------------------------------------------
__global__ __launch_bounds__(256, 3) void gemm_score_fused(
    const unsigned short* __restrict__ xb, const unsigned short* __restrict__ wbT,
    const float* __restrict__ b_attn,
    unsigned short* __restrict__ Qb, unsigned short* __restrict__ Kb,
    unsigned short* __restrict__ Vt,
    const float* __restrict__ q0, const float* __restrict__ k0,
    float* __restrict__ Sbuf, float* __restrict__ partials) {
  __shared__ __align__(16) unsigned short smem_u[17408];  // 34816 B
  int bid = blockIdx.x;
  int tid = threadIdx.x;

  if (bid >= 576) {
    // ---------------- score0 path (verbatim standalone structure) ----------
    int t = bid - 576;
    int b = t >> 10;
    int rem = t & 1023;
    int it = rem >> 5, jt = rem & 31;
    int i0 = it * 64, j0 = jt * 64;
    if (jt > it) {
      if (tid < 64) partials[((size_t)(b * 32 + it)) * TT + j0 + tid] = 0.f;
      return;
    }
    float (*Qs)[64] = (float(*)[64])smem_u;                  // 16384 B
    float (*Ks)[64] = (float(*)[64])(smem_u + 8192);         // 16384 B
    int row = tid >> 2;
    int dq = (tid & 3) << 2;
    const float* qb = q0 + (size_t)((b * TT) + i0 + row) * HD;
    const float* kb = k0 + (size_t)((b * TT) + j0 + row) * HD;
#pragma unroll
    for (int rep = 0; rep < 4; ++rep) {
      int d = dq + rep * 16;
      float4 qv = *(const float4*)(qb + d);
      float4 kv = *(const float4*)(kb + d);
      Qs[d + 0][row] = qv.x; Qs[d + 1][row] = qv.y;
      Qs[d + 2][row] = qv.z; Qs[d + 3][row] = qv.w;
      Ks[d + 0][row] = kv.x; Ks[d + 1][row] = kv.y;
      Ks[d + 2][row] = kv.z; Ks[d + 3][row] = kv.w;
    }
    __syncthreads();
    int tx = tid & 15, ty = tid >> 4;
    float acc[4][4] = {};
#pragma unroll 8
    for (int kk = 0; kk < 64; ++kk) {
      float4 a4 = *(const float4*)&Qs[kk][ty << 2];
      float4 b4 = *(const float4*)&Ks[kk][tx << 2];
      float a[4] = {a4.x, a4.y, a4.z, a4.w};
      float bb[4] = {b4.x, b4.y, b4.z, b4.w};
#pragma unroll
      for (int ii = 0; ii < 4; ++ii)
#pragma unroll
        for (int jj = 0; jj < 4; ++jj) acc[ii][jj] += a[ii] * bb[jj];
    }
    float red4[4] = {0.f, 0.f, 0.f, 0.f};
#pragma unroll
    for (int ii = 0; ii < 4; ++ii) {
      int r = i0 + (ty << 2) + ii;
      int gi = (b * TT) + r;
      float ov[4];
#pragma unroll
      for (int jj = 0; jj < 4; ++jj) {
        ov[jj] = fmaxf(acc[ii][jj] * 0.125f, 0.f);
        int j = j0 + (tx << 2) + jj;
        if (j >= 1 && j < r) red4[jj] += ov[jj];
      }
      float4 o; o.x = ov[0]; o.y = ov[1]; o.z = ov[2]; o.w = ov[3];
      *(float4*)(Sbuf + (size_t)gi * TT + j0 + (tx << 2)) = o;
    }
    __syncthreads();  // everyone done reading Qs
    *(float4*)&Qs[ty][tx << 2] = *(float4*)red4;
    __syncthreads();
    if (tid < 64) {
      float cs = 0.f;
#pragma unroll
      for (int t2 = 0; t2 < 16; ++t2) cs += Qs[t2][tid];
      partials[((size_t)(b * 32 + it)) * TT + j0 + tid] = cs;
    }
    return;
  }

  // ---------------- bf16 MFMA qkv path ----------------
  unsigned short (*Alds)[128][32] = (unsigned short(*)[128][32])smem_u;
  unsigned short (*Blds)[128][32] = (unsigned short(*)[128][32])(smem_u + 8192);
  unsigned short (*Vlds)[136]     = (unsigned short(*)[136])smem_u;

  int mt = bid & 31, nt = bid >> 5;
  int sec = nt / 6, h0 = (nt % 6) * 2;
  int wave = threadIdx.x >> 6, lane = threadIdx.x & 63;
  int lr = lane & 15, lg = lane >> 4;
  int m0 = mt * 128;
  int n0 = nt * 128;

  int srow = lane >> 2;                 // 0..15 staging row within segment
  int sslot = (lane & 3) ^ (srow & 3);  // pre-swizzled source k-slot (16B units)

#define STAGE_AB(BUF, K0)                                                       \
  {                                                                             \
    _Pragma("unroll")                                                           \
    for (int p = 0; p < 2; ++p) {                                               \
      int ar = wave * 32 + p * 16 + srow;                                       \
      gload_lds16(xb + (size_t)(m0 + ar) * CC + (K0) + (sslot << 3),            \
                  &Alds[BUF][wave * 32 + p * 16][0]);                           \
      gload_lds16(wbT + (size_t)(n0 + ar) * CC + (K0) + (sslot << 3),           \
                  &Blds[BUF][wave * 32 + p * 16][0]);                           \
    }                                                                           \
  }

  f32x4 acc[2][8];
#pragma unroll
  for (int mi = 0; mi < 2; ++mi)
#pragma unroll
    for (int nj = 0; nj < 8; ++nj) acc[mi][nj] = (f32x4){0.f, 0.f, 0.f, 0.f};

  STAGE_AB(0, 0)
  __syncthreads();

  int fslot = lg ^ (lr & 3);  // frag read slot (same involution)
  for (int kt = 0; kt < 24; ++kt) {
    int cur = kt & 1;
    if (kt < 23) STAGE_AB(cur ^ 1, (kt + 1) * 32)
    bf16x8 af[2], bf[8];
#pragma unroll
    for (int mi = 0; mi < 2; ++mi)
      af[mi] = *(const bf16x8*)&Alds[cur][wave * 32 + mi * 16 + lr][fslot << 3];
#pragma unroll
    for (int nj = 0; nj < 8; ++nj)
      bf[nj] = *(const bf16x8*)&Blds[cur][nj * 16 + lr][fslot << 3];
    __builtin_amdgcn_s_setprio(1);
#pragma unroll
    for (int nj = 0; nj < 8; ++nj)
#pragma unroll
      for (int mi = 0; mi < 2; ++mi)
        acc[mi][nj] = __builtin_amdgcn_mfma_f32_16x16x32_bf16(af[mi], bf[nj], acc[mi][nj], 0, 0, 0);
    __builtin_amdgcn_s_setprio(0);
    __syncthreads();
  }
#undef STAGE_AB

  int b = m0 >> 11;
  float bias[8];
#pragma unroll
  for (int nj = 0; nj < 8; ++nj) bias[nj] = b_attn[n0 + nj * 16 + lr];

  if (sec < 2) {
    // Q is pre-scaled by 1/8 (exact in bf16: exponent shift only)
    float qscale = (sec == 0) ? 0.125f : 1.0f;
    unsigned short* OutB = (sec == 0 ? Qb : Kb);
    int tbase = (m0 & 2047) + wave * 32 + lg * 4;
#pragma unroll
    for (int nj = 0; nj < 8; ++nj) {
      int h = h0 + (nj >> 2);
      int d = (nj & 3) * 16 + lr;
      unsigned short* Out = OutB + (size_t)(b * NH + h) * TT * HD;
#pragma unroll
      for (int mi = 0; mi < 2; ++mi)
#pragma unroll
        for (int r = 0; r < 4; ++r) {
          int t = tbase + mi * 16 + r;
          Out[(size_t)t * HD + d] = f2b((acc[mi][nj][r] + bias[nj]) * qscale);
        }
    }
  } else {
    int tl = wave * 32 + lg * 4;
#pragma unroll
    for (int mi = 0; mi < 2; ++mi)
#pragma unroll
      for (int r = 0; r < 4; ++r)
#pragma unroll
        for (int nj = 0; nj < 8; ++nj)
          Vlds[tl + mi * 16 + r][nj * 16 + lr] = f2b(acc[mi][nj][r] + bias[nj]);
    __syncthreads();
    int d = threadIdx.x & 63, tc = threadIdx.x >> 6;
    int tblk = (m0 & 2047);
#pragma unroll
    for (int hh = 0; hh < 2; ++hh) {
      unsigned short* Ov = Vt + ((size_t)(b * NH + h0 + hh) * HD + d) * TT + tblk + tc * 32;
      int c = hh * 64 + d;
#pragma unroll
      for (int i8 = 0; i8 < 4; ++i8) {
        ushort4 o0, o1;
        o0.x = Vlds[tc * 32 + i8 * 8 + 0][c]; o0.y = Vlds[tc * 32 + i8 * 8 + 1][c];
        o0.z = Vlds[tc * 32 + i8 * 8 + 2][c]; o0.w = Vlds[tc * 32 + i8 * 8 + 3][c];
        o1.x = Vlds[tc * 32 + i8 * 8 + 4][c]; o1.y = Vlds[tc * 32 + i8 * 8 + 5][c];
        o1.z = Vlds[tc * 32 + i8 * 8 + 6][c]; o1.w = Vlds[tc * 32 + i8 * 8 + 7][c];
        *(ushort4*)(Ov + i8 * 8) = o0;
        *(ushort4*)(Ov + i8 * 8 + 4) = o1;
      }
    }
  }
}

// ---------------------------------------------------------------------------
// Column-wise exclusive prefix scan over rows (64-row chunks). Emits
// E = exp(-FF) bf16 (j-swizzled) + ffpart row sums. 8-row load batching.
// Partials prefix unrolled x4 (independent load chains). EARLY EXIT for
// blocks whose whole column band lies above the diagonal.
// ---------------------------------------------------------------------------
__global__ __launch_bounds__(256) void scan_write(
    const float* __restrict__ Sbuf, const float* __restrict__ partials,
    unsigned short* __restrict__ Eb, float* __restrict__ ffpart) {
  int jb = blockIdx.x;
  int chunk = blockIdx.y, b = blockIdx.z;
  int r0 = chunk * 64;
  if (jb * 256 >= r0 + 64) {  // entire band above diagonal: FF=0, E unread
    if (threadIdx.x < 64)
      ffpart[((size_t)(b * 8) + jb) * TT + r0 + threadIdx.x] = 0.f;
    return;
  }
  int j = jb * 256 + threadIdx.x;
  const float* pbase = partials + ((size_t)(b * 32)) * TT + j;
  float s0 = 0.f, s1 = 0.f, s2 = 0.f, s3 = 0.f;
  int c = 0;
  for (; c + 3 < chunk; c += 4) {
    s0 += pbase[(size_t)(c + 0) * TT];
    s1 += pbase[(size_t)(c + 1) * TT];
    s2 += pbase[(size_t)(c + 2) * TT];
    s3 += pbase[(size_t)(c + 3) * TT];
  }
  for (; c < chunk; ++c) s0 += pbase[(size_t)c * TT];
  float run = (s0 + s1) + (s2 + s3);
  int jswz = (j & ~63) | ((j & 15) << 2) | ((j >> 4) & 3);
  const float* base = Sbuf + (size_t)(b * TT + r0) * TT + j;
  unsigned short* ebase = Eb + (size_t)(b * TT + r0) * TT + jswz;
  __shared__ float wsum[4][64];
  int wv = threadIdx.x >> 6;
  for (int rb = 0; rb < 64; rb += 8) {
    float v[8];
#pragma unroll
    for (int u = 0; u < 8; ++u) {
      int r = r0 + rb + u;
      v[u] = (j >= 1 && j < r) ? base[(size_t)(rb + u) * TT] : 0.f;
    }
#pragma unroll
    for (int u = 0; u < 8; ++u) {
      int rr = rb + u;
      ebase[(size_t)rr * TT] = f2b(__expf(-run));  // E (bf16, natural-e)
      float c1 = fminf(run, 1.f);                  // run >= 0 always
#pragma unroll
      for (int o = 1; o < 64; o <<= 1) c1 += __shfl_xor(c1, o);
      if ((threadIdx.x & 63) == 0) wsum[wv][rr] = c1;
      run += v[u];
    }
  }
  __syncthreads();
  if (threadIdx.x < 64)
    ffpart[((size_t)(b * 8) + jb) * TT + r0 + threadIdx.x] =
        wsum[0][threadIdx.x] + wsum[1][threadIdx.x] +
        wsum[2][threadIdx.x] + wsum[3][threadIdx.x];
}

// ---------------------------------------------------------------------------
// FUSED attention + M writer (1D grid, 1280 blocks):
//   bid <  768 : bf16 MFMA flash attention (R9 form + balanced g4) — LONG
//                blocks first; XCD = bid%8 serves one batch / 3 heads.
//   else       : M writer — short HBM-store blocks that backfill.
// ---------------------------------------------------------------------------
__global__ __launch_bounds__(256, 3) void attn_m_fused(
    const unsigned short* __restrict__ Qb, const unsigned short* __restrict__ Kb,
    const unsigned short* __restrict__ Vt, const unsigned short* __restrict__ Eb,
    unsigned short* __restrict__ yhb,
    const float* __restrict__ ffpart, float* __restrict__ Mout) {
  int bid = blockIdx.x;
  if (bid >= 768) {
    int idx4 = (bid - 768) * 256 + threadIdx.x;
    int stride = (gridDim.x - 768) * 256;
    for (; idx4 < M_ELEMS / 4; idx4 += stride) {
      int idx = idx4 << 2;
      int j = idx & (TT - 1);
      int i = (idx >> 11) & (TT - 1);
      int b = idx >> 22;
      const float* fp = ffpart + ((size_t)(b * 8)) * TT + j;
      float4 s = make_float4(0.f, 0.f, 0.f, 0.f);
#pragma unroll
      for (int p = 0; p < 8; ++p) {
        float4 v = *(const float4*)(fp + (size_t)p * TT);
        s.x += v.x; s.y += v.y; s.z += v.z; s.w += v.w;
      }
      float fi = (float)i;
      float4 o = make_float4(fi - s.x, fi - s.y, fi - s.z, fi - s.w);
      *(float4*)(Mout + idx) = o;
    }
    return;
  }
  int xbh = bid % 24;
  int b = (xbh >> 2) & 1;
  int h = ((xbh >> 3) << 2) | (xbh & 3);
  int yy = bid / 24;
  int g4 = (yy & 1) ? (yy >> 1) : (31 - (yy >> 1));  // balanced interleave
  int wave = threadIdx.x >> 6, lane = threadIdx.x & 63;
  int lr = lane & 15, lg = lane >> 4;
  int i0 = g4 * 64 + wave * 16;
  int bh = b * NH + h;
  const unsigned short* Qh = Qb + (size_t)bh * TT * HD;
  const unsigned short* Kh = Kb + (size_t)bh * TT * HD;
  const unsigned short* Vh = Vt + (size_t)bh * HD * TT;
  const unsigned short* Erow = Eb + ((size_t)(b * TT) + i0 + lg * 4) * TT + 4 * lr;

  __shared__ __align__(16) unsigned short Ksh[2][64][64];
  __shared__ __align__(16) unsigned short Vsh[2][64][64];
  __shared__ __align__(16) unsigned short Plds[4][16][80];

  int rowoff = lane >> 3;            // 0..7 within an 8-row staging segment
  int sslot  = (lane & 7) ^ rowoff;  // pre-swizzled source slot (16B units)

  bf16x8 qf[2];
#pragma unroll
  for (int ks = 0; ks < 2; ++ks)
    qf[ks] = *(const bf16x8*)(Qh + (size_t)(i0 + lr) * HD + ks * 32 + lg * 8);

  f32x4 acc[4];
  float lrun[4] = {0.f, 0.f, 0.f, 0.f};  // per-lane partial of softmax denom
#pragma unroll
  for (int q = 0; q < 4; ++q) acc[q] = (f32x4){0.f, 0.f, 0.f, 0.f};

#define STAGE_KV(BUF, J0)                                                      \
  {                                                                            \
    _Pragma("unroll")                                                          \
    for (int p = 0; p < 2; ++p) {                                              \
      int r0 = wave * 16 + p * 8;                                              \
      gload_lds16(Kh + (size_t)((J0) + r0 + rowoff) * HD + sslot * 8,          \
                  &Ksh[BUF][r0][0]);                                           \
      gload_lds16(Vh + (size_t)(r0 + rowoff) * TT + (J0) + sslot * 8,          \
                  &Vsh[BUF][r0][0]);                                           \
    }                                                                          \
  }

  STAGE_KV(0, 0)
  __syncthreads();

  for (int kt = 0; kt <= g4; ++kt) {
    int cur = kt & 1;
    int j0 = kt * 64;
    if (kt < g4) STAGE_KV(cur ^ 1, j0 + 64)

    // E for current tile (4 x 8B vector loads, swizzled layout)
    ushort4 ev[4];
#pragma unroll
    for (int r = 0; r < 4; ++r)
      ev[r] = *(const ushort4*)(Erow + (size_t)r * TT + j0);

    // ---- QK^T from swizzled LDS ----
    f32x4 s[4];
    __builtin_amdgcn_s_setprio(1);
#pragma unroll
    for (int nj = 0; nj < 4; ++nj) {
      int row = nj * 16 + lr;
      int sw = row & 7;
      bf16x8 k0f = *(const bf16x8*)&Ksh[cur][row][(lg ^ sw) << 3];
      bf16x8 k1f = *(const bf16x8*)&Ksh[cur][row][((4 + lg) ^ sw) << 3];
      f32x4 z = (f32x4){0.f, 0.f, 0.f, 0.f};
      z = __builtin_amdgcn_mfma_f32_16x16x32_bf16(qf[0], k0f, z, 0, 0, 0);
      s[nj] = __builtin_amdgcn_mfma_f32_16x16x32_bf16(qf[1], k1f, z, 0, 0, 0);
    }
    __builtin_amdgcn_s_setprio(0);

    // ---- causal mask (diagonal tile only) ----
    int ibase = i0 + lg * 4;
    if (kt == g4) {
#pragma unroll
      for (int nj = 0; nj < 4; ++nj)
#pragma unroll
        for (int r = 0; r < 4; ++r)
          if (j0 + nj * 16 + lr > ibase + r) s[nj][r] = -1e30f;
    }

    // ---- P = E * exp(s); per-lane partial l; stash bf16 P in LDS ----
#pragma unroll
    for (int r = 0; r < 4; ++r) {
      float p0 = b2f(ev[r].x) * __expf(s[0][r]);
      float p1 = b2f(ev[r].y) * __expf(s[1][r]);
      float p2 = b2f(ev[r].z) * __expf(s[2][r]);
      float p3 = b2f(ev[r].w) * __expf(s[3][r]);
      lrun[r] += (p0 + p1) + (p2 + p3);
      Plds[wave][lg * 4 + r][0 * 16 + lr] = f2b(p0);
      Plds[wave][lg * 4 + r][1 * 16 + lr] = f2b(p1);
      Plds[wave][lg * 4 + r][2 * 16 + lr] = f2b(p2);
      Plds[wave][lg * 4 + r][3 * 16 + lr] = f2b(p3);
    }

    // ---- PV from swizzled LDS ----
    bf16x8 pa0 = *(const bf16x8*)&Plds[wave][lr][lg * 8];
    bf16x8 pa1 = *(const bf16x8*)&Plds[wave][lr][32 + lg * 8];
    __builtin_amdgcn_s_setprio(1);
#pragma unroll
    for (int nd = 0; nd < 4; ++nd) {
      int row = nd * 16 + lr;
      int sw = row & 7;
      bf16x8 v0f = *(const bf16x8*)&Vsh[cur][row][(lg ^ sw) << 3];
      bf16x8 v1f = *(const bf16x8*)&Vsh[cur][row][((4 + lg) ^ sw) << 3];
      acc[nd] = __builtin_amdgcn_mfma_f32_16x16x32_bf16(pa0, v0f, acc[nd], 0, 0, 0);
      acc[nd] = __builtin_amdgcn_mfma_f32_16x16x32_bf16(pa1, v1f, acc[nd], 0, 0, 0);
    }
    __builtin_amdgcn_s_setprio(0);

    __syncthreads();
  }
#undef STAGE_KV

  // ---- epilogue: one l-reduction across the 16 lr lanes, then store ----
#pragma unroll
  for (int r = 0; r < 4; ++r) {
    lrun[r] += __shfl_xor(lrun[r], 1);
    lrun[r] += __shfl_xor(lrun[r], 2);
    lrun[r] += __shfl_xor(lrun[r], 4);
    lrun[r] += __shfl_xor(lrun[r], 8);
    float inv = 1.f / lrun[r];
    int ig = i0 + lg * 4 + r;
    unsigned short* ob = yhb + (size_t)(b * TT + ig) * CC + h * HD;
#pragma unroll
    for (int nd = 0; nd < 4; ++nd)
      ob[nd * 16 + lr] = f2b(acc[nd][r] * inv);
  }
}

// ---------------------------------------------------------------------------
// proj GEMM: y = yhb @ wpT^T + b_proj (128x128 MFMA tile). Grid (32, 6).
// ---------------------------------------------------------------------------
__global__ __launch_bounds__(256, 3) void gemm_proj_bf16(
    const unsigned short* __restrict__ yhb, const unsigned short* __restrict__ wpT,
    const float* __restrict__ b_proj, float* __restrict__ y) {
  __shared__ __align__(16) unsigned short Alds[2][128][32];
  __shared__ __align__(16) unsigned short Blds[2][128][32];
  int mt = blockIdx.x, nt = blockIdx.y;
  int wave = threadIdx.x >> 6, lane = threadIdx.x & 63;
  int lr = lane & 15, lg = lane >> 4;
  int m0 = mt * 128;
  int n0 = nt * 128;

  int srow = lane >> 2;
  int sslot = (lane & 3) ^ (srow & 3);

#define STAGE_AB(BUF, K0)                                                       \
  {                                                                             \
    _Pragma("unroll")                                                           \
    for (int p = 0; p < 2; ++p) {                                               \
      int ar = wave * 32 + p * 16 + srow;                                       \
      gload_lds16(yhb + (size_t)(m0 + ar) * CC + (K0) + (sslot << 3),           \
                  &Alds[BUF][wave * 32 + p * 16][0]);                           \
      gload_lds16(wpT + (size_t)(n0 + ar) * CC + (K0) + (sslot << 3),           \
                  &Blds[BUF][wave * 32 + p * 16][0]);                           \
    }                                                                           \
  }

  f32x4 acc[2][8];
#pragma unroll
  for (int mi = 0; mi < 2; ++mi)
#pragma unroll
    for (int nj = 0; nj < 8; ++nj) acc[mi][nj] = (f32x4){0.f, 0.f, 0.f, 0.f};

  STAGE_AB(0, 0)
  __syncthreads();

  int fslot = lg ^ (lr & 3);
  for (int kt = 0; kt < 24; ++kt) {
    int cur = kt & 1;
    if (kt < 23) STAGE_AB(cur ^ 1, (kt + 1) * 32)
    bf16x8 af[2], bf[8];
#pragma unroll
    for (int mi = 0; mi < 2; ++mi)
      af[mi] = *(const bf16x8*)&Alds[cur][wave * 32 + mi * 16 + lr][fslot << 3];
#pragma unroll
    for (int nj = 0; nj < 8; ++nj)
      bf[nj] = *(const bf16x8*)&Blds[cur][nj * 16 + lr][fslot << 3];
    __builtin_amdgcn_s_setprio(1);
#pragma unroll
    for (int nj = 0; nj < 8; ++nj)
#pragma unroll
      for (int mi = 0; mi < 2; ++mi)
        acc[mi][nj] = __builtin_amdgcn_mfma_f32_16x16x32_bf16(af[mi], bf[nj], acc[mi][nj], 0, 0, 0);
    __builtin_amdgcn_s_setprio(0);
    __syncthreads();
  }
#undef STAGE_AB

  float bias[8];
#pragma unroll
  for (int nj = 0; nj < 8; ++nj) bias[nj] = b_proj[n0 + nj * 16 + lr];
#pragma unroll
  for (int mi = 0; mi < 2; ++mi)
#pragma unroll
    for (int r = 0; r < 4; ++r) {
      int m = m0 + wave * 32 + mi * 16 + lg * 4 + r;
#pragma unroll
      for (int nj = 0; nj < 8; ++nj)
        y[(size_t)m * CC + n0 + nj * 16 + lr] = acc[mi][nj][r] + bias[nj];
    }
}

// ---------------------------------------------------------------------------
extern "C" void kernel_launch(void* const* d_in, const int* in_sizes, int n_in,
                              void* d_out, int out_size, void* d_ws, size_t ws_size,
                              hipStream_t stream) {
  const float* x      = (const float*)d_in[0];
  const float* w_attn = (const float*)d_in[1];
  const float* b_attn = (const float*)d_in[2];
  const float* w_proj = (const float*)d_in[3];
  const float* b_proj = (const float*)d_in[4];

  float* y    = (float*)d_out;          // [B,T,C]
  float* Mreg = y + Y_ELEMS;            // [B,T,T]: S0 (scratch) -> M (final)

  float* ws = (float*)d_ws;
  float* q0       = ws;                               // B*T*64
  float* k0       = q0 + (size_t)BB * TT * HD;
  float* partials = k0 + (size_t)BB * TT * HD;        // B*32*T
  float* ffpart   = partials + (size_t)BB * 32 * TT;  // B*8*T
  unsigned short* xb  = (unsigned short*)(ffpart + (size_t)BB * 8 * TT);  // B*T*C
  unsigned short* wbT = xb + (size_t)Y_ELEMS;                 // 2304*768
  unsigned short* wpT = wbT + (size_t)N3 * CC;                // 768*768
  unsigned short* Qb  = wpT + (size_t)CC * CC;                // B*NH*T*HD
  unsigned short* Kb  = Qb + (size_t)BB * NH * TT * HD;
  unsigned short* Vt  = Kb + (size_t)BB * NH * TT * HD;
  unsigned short* yhb = Vt + (size_t)BB * NH * TT * HD;       // B*T*C
  unsigned short* Eb  = yhb + (size_t)Y_ELEMS;                // B*T*T bf16 (16.8MB)
  // total ws usage ~= 46 MB

  // 1. fused prep: qk0 (long blocks first) + packs + weight transposes
  prep_fused<<<2368, 256, 0, stream>>>(x, w_attn, w_proj, b_attn,
                                       xb, wbT, wpT, q0, k0);
  // 2. fused QKV MFMA GEMM (576 long blocks first) + score0 (short backfill)
  gemm_score_fused<<<2624, 256, 0, stream>>>(
      xb, wbT, b_attn, Qb, Kb, Vt, q0, k0, Mreg, partials);
  // 3. scan: E = exp(-FF) bf16 (jswz) + ffpart row sums; upper-tri early-exit
  scan_write<<<dim3(8, 32, BB), 256, 0, stream>>>(Mreg, partials, Eb, ffpart);
  // 4. fused attention (768 long blocks first) + M writer (backfill stores)
  attn_m_fused<<<1280, 256, 0, stream>>>(Qb, Kb, Vt, Eb, yhb, ffpart, Mreg);
  // 5. proj GEMM (128x128)
  gemm_proj_bf16<<<dim3(32, 6), 256, 0, stream>>>(yhb, wpT, b_proj, y);
}

// Round 21
// 155.610 us; speedup vs baseline: 1.0913x; 1.0012x over previous
//
#include <hip/hip_runtime.h>
#include <cstddef>

// Problem constants
#define TT 2048
#define BB 2
#define CC 768
#define NH 12
#define HD 64
#define N3 2304          // 3*NH*HD
#define Y_ELEMS (BB*TT*CC)          // 3145728
#define M_ELEMS (BB*TT*TT)          // 8388608

typedef __attribute__((ext_vector_type(8))) short bf16x8;
typedef __attribute__((ext_vector_type(4))) float f32x4;

__device__ inline unsigned short f2b(float f) {
  union { float f; unsigned u; } v; v.f = f;
  unsigned r = (v.u + 0x7FFFu + ((v.u >> 16) & 1u)) >> 16;
  return (unsigned short)r;
}
__device__ inline float b2f(unsigned short u) {
  union { unsigned u; float f; } v; v.u = (unsigned)u << 16; return v.f;
}

// async global -> LDS, 16B per lane; lds dest is wave-uniform base, HW adds lane*16
__device__ inline void gload_lds16(const unsigned short* g, unsigned short* l) {
  __builtin_amdgcn_global_load_lds(
      (const __attribute__((address_space(1))) unsigned int*)g,
      (__attribute__((address_space(3))) unsigned int*)l, 16, 0, 0);
}

// ---------------------------------------------------------------------------
// FUSED prep + head-0 qk kernel (1D grid, 2368 blocks):
//   bid <   256 : fp32 GEMM q0/k0 (32x64 tile) — LONG blocks first.
//   bid <  1792 : pack x (fp32 -> bf16)
//   bid <  2224 : transpose-pack w_attn -> wbT
//   else        : transpose-pack w_proj -> wpT
// ---------------------------------------------------------------------------
__global__ __launch_bounds__(256) void prep_fused(
    const float* __restrict__ x, const float* __restrict__ w_attn,
    const float* __restrict__ w_proj, const float* __restrict__ b_attn,
    unsigned short* __restrict__ xb, unsigned short* __restrict__ wbT,
    unsigned short* __restrict__ wpT,
    float* __restrict__ q0, float* __restrict__ k0) {
  int bid = blockIdx.x;
  int tid = threadIdx.x;
  if (bid < 256) {
    __shared__ float As[16][32];
    __shared__ float Bs[16][64];
    int sec = bid >> 7;
    int mt = bid & 127;
    const float* Bw = w_attn + sec * CC;
    float* Out = sec ? k0 : q0;
    int tx = tid & 15, ty = tid >> 4;
    int m0 = mt * 32;

    int arow = tid >> 3;
    int acol2 = (tid & 7) << 1;
    int brow = tid >> 4;
    int bcol4 = (tid & 15) << 2;

    const float* Aptr = x + (size_t)(m0 + arow) * CC + acol2;
    const float* Bptr = Bw + (size_t)brow * N3 + bcol4;

    float acc[2][4] = {};
    for (int k0_ = 0; k0_ < CC; k0_ += 16) {
      float2 av = *(const float2*)(Aptr + k0_);
      float4 bv = *(const float4*)(Bptr + (size_t)k0_ * N3);
      As[acol2 + 0][arow] = av.x;
      As[acol2 + 1][arow] = av.y;
      *(float4*)&Bs[brow][bcol4] = bv;
      __syncthreads();
#pragma unroll
      for (int kk = 0; kk < 16; ++kk) {
        float2 a2 = *(const float2*)&As[kk][ty << 1];
        float4 b4 = *(const float4*)&Bs[kk][tx << 2];
        float a[2] = {a2.x, a2.y};
        float b[4] = {b4.x, b4.y, b4.z, b4.w};
#pragma unroll
        for (int ii = 0; ii < 2; ++ii)
#pragma unroll
          for (int jj = 0; jj < 4; ++jj) acc[ii][jj] += a[ii] * b[jj];
      }
      __syncthreads();
    }
    float4 bv = *(const float4*)(b_attn + sec * CC + (tx << 2));
#pragma unroll
    for (int ii = 0; ii < 2; ++ii) {
      int m = m0 + (ty << 1) + ii;
      float4 o;
      o.x = acc[ii][0] + bv.x;
      o.y = acc[ii][1] + bv.y;
      o.z = acc[ii][2] + bv.z;
      o.w = acc[ii][3] + bv.w;
      *(float4*)(Out + (size_t)m * HD + (tx << 2)) = o;
    }
    return;
  }
  if (bid < 1792) {
    size_t i = ((size_t)(bid - 256) * 256 + tid) * 8;
    float4 a = *(const float4*)(x + i);
    float4 b = *(const float4*)(x + i + 4);
    ushort4 o0, o1;
    o0.x = f2b(a.x); o0.y = f2b(a.y); o0.z = f2b(a.z); o0.w = f2b(a.w);
    o1.x = f2b(b.x); o1.y = f2b(b.y); o1.z = f2b(b.z); o1.w = f2b(b.w);
    *(ushort4*)(xb + i) = o0;
    *(ushort4*)(xb + i + 4) = o1;
    return;
  }
  const float* W;
  unsigned short* WT;
  int N, kt, nt;
  if (bid < 2224) {
    int t = bid - 1792;
    W = w_attn; WT = wbT; N = N3;
    kt = t % 12; nt = t / 12;
  } else {
    int t = bid - 2224;
    W = w_proj; WT = wpT; N = CC;
    kt = t % 12; nt = t / 12;
  }
  __shared__ float tile[64][65];
  int r = tid >> 4, c4 = (tid & 15) << 2;
#pragma unroll
  for (int rep = 0; rep < 4; ++rep) {
    int row = rep * 16 + r;
    float4 v = *(const float4*)(W + (size_t)(kt * 64 + row) * N + nt * 64 + c4);
    tile[row][c4 + 0] = v.x; tile[row][c4 + 1] = v.y;
    tile[row][c4 + 2] = v.z; tile[row][c4 + 3] = v.w;
  }
  __syncthreads();
#pragma unroll
  for (int rep = 0; rep < 4; ++rep) {
    int nrow = rep * 16 + r;
    ushort4 o;
    o.x = f2b(tile[c4 + 0][nrow]); o.y = f2b(tile[c4 + 1][nrow]);
    o.z = f2b(tile[c4 + 2][nrow]); o.w = f2b(tile[c4 + 3][nrow]);
    *(ushort4*)(WT + (size_t)(nt * 64 + nrow) * CC + kt * 64 + c4) = o;
  }
}

// ---------------------------------------------------------------------------
// FUSED QKV MFMA GEMM + head-0 scores. 1D grid, 2624 blocks:
//   bid <  576 : bf16 MFMA qkv (128x128 tile) — LONG blocks, dispatched first
//   else       : score0 (fp32 64x64 tile + fused column partials) — short
//                blocks that backfill CUs as gemm blocks retire.
// LDS: one 34816B buffer overlaid by both paths.
// ---------------------------------------------------------------------------
__global__ __launch_bounds__(256, 3) void gemm_score_fused(
    const unsigned short* __restrict__ xb, const unsigned short* __restrict__ wbT,
    const float* __restrict__ b_attn,
    unsigned short* __restrict__ Qb, unsigned short* __restrict__ Kb,
    unsigned short* __restrict__ Vt,
    const float* __restrict__ q0, const float* __restrict__ k0,
    float* __restrict__ Sbuf, float* __restrict__ partials) {
  __shared__ __align__(16) unsigned short smem_u[17408];  // 34816 B
  int bid = blockIdx.x;
  int tid = threadIdx.x;

  if (bid >= 576) {
    // ---------------- score0 path (verbatim standalone structure) ----------
    int t = bid - 576;
    int b = t >> 10;
    int rem = t & 1023;
    int it = rem >> 5, jt = rem & 31;
    int i0 = it * 64, j0 = jt * 64;
    if (jt > it) {
      if (tid < 64) partials[((size_t)(b * 32 + it)) * TT + j0 + tid] = 0.f;
      return;
    }
    float (*Qs)[64] = (float(*)[64])smem_u;                  // 16384 B
    float (*Ks)[64] = (float(*)[64])(smem_u + 8192);         // 16384 B
    int row = tid >> 2;
    int dq = (tid & 3) << 2;
    const float* qb = q0 + (size_t)((b * TT) + i0 + row) * HD;
    const float* kb = k0 + (size_t)((b * TT) + j0 + row) * HD;
#pragma unroll
    for (int rep = 0; rep < 4; ++rep) {
      int d = dq + rep * 16;
      float4 qv = *(const float4*)(qb + d);
      float4 kv = *(const float4*)(kb + d);
      Qs[d + 0][row] = qv.x; Qs[d + 1][row] = qv.y;
      Qs[d + 2][row] = qv.z; Qs[d + 3][row] = qv.w;
      Ks[d + 0][row] = kv.x; Ks[d + 1][row] = kv.y;
      Ks[d + 2][row] = kv.z; Ks[d + 3][row] = kv.w;
    }
    __syncthreads();
    int tx = tid & 15, ty = tid >> 4;
    float acc[4][4] = {};
#pragma unroll 8
    for (int kk = 0; kk < 64; ++kk) {
      float4 a4 = *(const float4*)&Qs[kk][ty << 2];
      float4 b4 = *(const float4*)&Ks[kk][tx << 2];
      float a[4] = {a4.x, a4.y, a4.z, a4.w};
      float bb[4] = {b4.x, b4.y, b4.z, b4.w};
#pragma unroll
      for (int ii = 0; ii < 4; ++ii)
#pragma unroll
        for (int jj = 0; jj < 4; ++jj) acc[ii][jj] += a[ii] * bb[jj];
    }
    float red4[4] = {0.f, 0.f, 0.f, 0.f};
#pragma unroll
    for (int ii = 0; ii < 4; ++ii) {
      int r = i0 + (ty << 2) + ii;
      int gi = (b * TT) + r;
      float ov[4];
#pragma unroll
      for (int jj = 0; jj < 4; ++jj) {
        ov[jj] = fmaxf(acc[ii][jj] * 0.125f, 0.f);
        int j = j0 + (tx << 2) + jj;
        if (j >= 1 && j < r) red4[jj] += ov[jj];
      }
      float4 o; o.x = ov[0]; o.y = ov[1]; o.z = ov[2]; o.w = ov[3];
      *(float4*)(Sbuf + (size_t)gi * TT + j0 + (tx << 2)) = o;
    }
    __syncthreads();  // everyone done reading Qs
    *(float4*)&Qs[ty][tx << 2] = *(float4*)red4;
    __syncthreads();
    if (tid < 64) {
      float cs = 0.f;
#pragma unroll
      for (int t2 = 0; t2 < 16; ++t2) cs += Qs[t2][tid];
      partials[((size_t)(b * 32 + it)) * TT + j0 + tid] = cs;
    }
    return;
  }

  // ---------------- bf16 MFMA qkv path ----------------
  unsigned short (*Alds)[128][32] = (unsigned short(*)[128][32])smem_u;
  unsigned short (*Blds)[128][32] = (unsigned short(*)[128][32])(smem_u + 8192);
  unsigned short (*Vlds)[136]     = (unsigned short(*)[136])smem_u;

  int mt = bid & 31, nt = bid >> 5;
  int sec = nt / 6, h0 = (nt % 6) * 2;
  int wave = threadIdx.x >> 6, lane = threadIdx.x & 63;
  int lr = lane & 15, lg = lane >> 4;
  int m0 = mt * 128;
  int n0 = nt * 128;

  int srow = lane >> 2;                 // 0..15 staging row within segment
  int sslot = (lane & 3) ^ (srow & 3);  // pre-swizzled source k-slot (16B units)

#define STAGE_AB(BUF, K0)                                                       \
  {                                                                             \
    _Pragma("unroll")                                                           \
    for (int p = 0; p < 2; ++p) {                                               \
      int ar = wave * 32 + p * 16 + srow;                                       \
      gload_lds16(xb + (size_t)(m0 + ar) * CC + (K0) + (sslot << 3),            \
                  &Alds[BUF][wave * 32 + p * 16][0]);                           \
      gload_lds16(wbT + (size_t)(n0 + ar) * CC + (K0) + (sslot << 3),           \
                  &Blds[BUF][wave * 32 + p * 16][0]);                           \
    }                                                                           \
  }

  f32x4 acc[2][8];
#pragma unroll
  for (int mi = 0; mi < 2; ++mi)
#pragma unroll
    for (int nj = 0; nj < 8; ++nj) acc[mi][nj] = (f32x4){0.f, 0.f, 0.f, 0.f};

  STAGE_AB(0, 0)
  __syncthreads();

  int fslot = lg ^ (lr & 3);  // frag read slot (same involution)
  for (int kt = 0; kt < 24; ++kt) {
    int cur = kt & 1;
    if (kt < 23) STAGE_AB(cur ^ 1, (kt + 1) * 32)
    bf16x8 af[2], bf[8];
#pragma unroll
    for (int mi = 0; mi < 2; ++mi)
      af[mi] = *(const bf16x8*)&Alds[cur][wave * 32 + mi * 16 + lr][fslot << 3];
#pragma unroll
    for (int nj = 0; nj < 8; ++nj)
      bf[nj] = *(const bf16x8*)&Blds[cur][nj * 16 + lr][fslot << 3];
    __builtin_amdgcn_s_setprio(1);
#pragma unroll
    for (int nj = 0; nj < 8; ++nj)
#pragma unroll
      for (int mi = 0; mi < 2; ++mi)
        acc[mi][nj] = __builtin_amdgcn_mfma_f32_16x16x32_bf16(af[mi], bf[nj], acc[mi][nj], 0, 0, 0);
    __builtin_amdgcn_s_setprio(0);
    __syncthreads();
  }
#undef STAGE_AB

  int b = m0 >> 11;
  float bias[8];
#pragma unroll
  for (int nj = 0; nj < 8; ++nj) bias[nj] = b_attn[n0 + nj * 16 + lr];

  if (sec < 2) {
    // Q is pre-scaled by 1/8 (exact in bf16: exponent shift only)
    float qscale = (sec == 0) ? 0.125f : 1.0f;
    unsigned short* OutB = (sec == 0 ? Qb : Kb);
    int tbase = (m0 & 2047) + wave * 32 + lg * 4;
#pragma unroll
    for (int nj = 0; nj < 8; ++nj) {
      int h = h0 + (nj >> 2);
      int d = (nj & 3) * 16 + lr;
      unsigned short* Out = OutB + (size_t)(b * NH + h) * TT * HD;
#pragma unroll
      for (int mi = 0; mi < 2; ++mi)
#pragma unroll
        for (int r = 0; r < 4; ++r) {
          int t = tbase + mi * 16 + r;
          Out[(size_t)t * HD + d] = f2b((acc[mi][nj][r] + bias[nj]) * qscale);
        }
    }
  } else {
    int tl = wave * 32 + lg * 4;
#pragma unroll
    for (int mi = 0; mi < 2; ++mi)
#pragma unroll
      for (int r = 0; r < 4; ++r)
#pragma unroll
        for (int nj = 0; nj < 8; ++nj)
          Vlds[tl + mi * 16 + r][nj * 16 + lr] = f2b(acc[mi][nj][r] + bias[nj]);
    __syncthreads();
    int d = threadIdx.x & 63, tc = threadIdx.x >> 6;
    int tblk = (m0 & 2047);
#pragma unroll
    for (int hh = 0; hh < 2; ++hh) {
      unsigned short* Ov = Vt + ((size_t)(b * NH + h0 + hh) * HD + d) * TT + tblk + tc * 32;
      int c = hh * 64 + d;
#pragma unroll
      for (int i8 = 0; i8 < 4; ++i8) {
        ushort4 o0, o1;
        o0.x = Vlds[tc * 32 + i8 * 8 + 0][c]; o0.y = Vlds[tc * 32 + i8 * 8 + 1][c];
        o0.z = Vlds[tc * 32 + i8 * 8 + 2][c]; o0.w = Vlds[tc * 32 + i8 * 8 + 3][c];
        o1.x = Vlds[tc * 32 + i8 * 8 + 4][c]; o1.y = Vlds[tc * 32 + i8 * 8 + 5][c];
        o1.z = Vlds[tc * 32 + i8 * 8 + 6][c]; o1.w = Vlds[tc * 32 + i8 * 8 + 7][c];
        *(ushort4*)(Ov + i8 * 8) = o0;
        *(ushort4*)(Ov + i8 * 8 + 4) = o1;
      }
    }
  }
}

// ---------------------------------------------------------------------------
// Column-wise exclusive prefix scan over rows (64-row chunks). Emits
// E = exp(-FF) bf16 (j-swizzled) + ffpart row sums. 8-row load batching.
// Partials prefix unrolled x4 (independent load chains). EARLY EXIT for
// blocks whose whole column band lies above the diagonal.
// ---------------------------------------------------------------------------
__global__ __launch_bounds__(256) void scan_write(
    const float* __restrict__ Sbuf, const float* __restrict__ partials,
    unsigned short* __restrict__ Eb, float* __restrict__ ffpart) {
  int jb = blockIdx.x;
  int chunk = blockIdx.y, b = blockIdx.z;
  int r0 = chunk * 64;
  if (jb * 256 >= r0 + 64) {  // entire band above diagonal: FF=0, E unread
    if (threadIdx.x < 64)
      ffpart[((size_t)(b * 8) + jb) * TT + r0 + threadIdx.x] = 0.f;
    return;
  }
  int j = jb * 256 + threadIdx.x;
  const float* pbase = partials + ((size_t)(b * 32)) * TT + j;
  float s0 = 0.f, s1 = 0.f, s2 = 0.f, s3 = 0.f;
  int c = 0;
  for (; c + 3 < chunk; c += 4) {
    s0 += pbase[(size_t)(c + 0) * TT];
    s1 += pbase[(size_t)(c + 1) * TT];
    s2 += pbase[(size_t)(c + 2) * TT];
    s3 += pbase[(size_t)(c + 3) * TT];
  }
  for (; c < chunk; ++c) s0 += pbase[(size_t)c * TT];
  float run = (s0 + s1) + (s2 + s3);
  int jswz = (j & ~63) | ((j & 15) << 2) | ((j >> 4) & 3);
  const float* base = Sbuf + (size_t)(b * TT + r0) * TT + j;
  unsigned short* ebase = Eb + (size_t)(b * TT + r0) * TT + jswz;
  __shared__ float wsum[4][64];
  int wv = threadIdx.x >> 6;
  for (int rb = 0; rb < 64; rb += 8) {
    float v[8];
#pragma unroll
    for (int u = 0; u < 8; ++u) {
      int r = r0 + rb + u;
      v[u] = (j >= 1 && j < r) ? base[(size_t)(rb + u) * TT] : 0.f;
    }
#pragma unroll
    for (int u = 0; u < 8; ++u) {
      int rr = rb + u;
      ebase[(size_t)rr * TT] = f2b(__expf(-run));  // E (bf16, natural-e)
      float c1 = fminf(run, 1.f);                  // run >= 0 always
#pragma unroll
      for (int o = 1; o < 64; o <<= 1) c1 += __shfl_xor(c1, o);
      if ((threadIdx.x & 63) == 0) wsum[wv][rr] = c1;
      run += v[u];
    }
  }
  __syncthreads();
  if (threadIdx.x < 64)
    ffpart[((size_t)(b * 8) + jb) * TT + r0 + threadIdx.x] =
        wsum[0][threadIdx.x] + wsum[1][threadIdx.x] +
        wsum[2][threadIdx.x] + wsum[3][threadIdx.x];
}

// ---------------------------------------------------------------------------
// FUSED attention + M writer (1D grid, 1280 blocks):
//   bid <  768 : bf16 MFMA flash attention (R9 form + balanced g4) — LONG
//                blocks first; XCD = bid%8 serves one batch / 3 heads.
//   else       : M writer — short HBM-store blocks that backfill.
// Plds stride 84 shorts (42 words): P-writes hit all 32 banks exactly once
// (conflict-free); pa b128 reads get 16 distinct start banks (even service).
// ---------------------------------------------------------------------------
__global__ __launch_bounds__(256, 3) void attn_m_fused(
    const unsigned short* __restrict__ Qb, const unsigned short* __restrict__ Kb,
    const unsigned short* __restrict__ Vt, const unsigned short* __restrict__ Eb,
    unsigned short* __restrict__ yhb,
    const float* __restrict__ ffpart, float* __restrict__ Mout) {
  int bid = blockIdx.x;
  if (bid >= 768) {
    int idx4 = (bid - 768) * 256 + threadIdx.x;
    int stride = (gridDim.x - 768) * 256;
    for (; idx4 < M_ELEMS / 4; idx4 += stride) {
      int idx = idx4 << 2;
      int j = idx & (TT - 1);
      int i = (idx >> 11) & (TT - 1);
      int b = idx >> 22;
      const float* fp = ffpart + ((size_t)(b * 8)) * TT + j;
      float4 s = make_float4(0.f, 0.f, 0.f, 0.f);
#pragma unroll
      for (int p = 0; p < 8; ++p) {
        float4 v = *(const float4*)(fp + (size_t)p * TT);
        s.x += v.x; s.y += v.y; s.z += v.z; s.w += v.w;
      }
      float fi = (float)i;
      float4 o = make_float4(fi - s.x, fi - s.y, fi - s.z, fi - s.w);
      *(float4*)(Mout + idx) = o;
    }
    return;
  }
  int xbh = bid % 24;
  int b = (xbh >> 2) & 1;
  int h = ((xbh >> 3) << 2) | (xbh & 3);
  int yy = bid / 24;
  int g4 = (yy & 1) ? (yy >> 1) : (31 - (yy >> 1));  // balanced interleave
  int wave = threadIdx.x >> 6, lane = threadIdx.x & 63;
  int lr = lane & 15, lg = lane >> 4;
  int i0 = g4 * 64 + wave * 16;
  int bh = b * NH + h;
  const unsigned short* Qh = Qb + (size_t)bh * TT * HD;
  const unsigned short* Kh = Kb + (size_t)bh * TT * HD;
  const unsigned short* Vh = Vt + (size_t)bh * HD * TT;
  const unsigned short* Erow = Eb + ((size_t)(b * TT) + i0 + lg * 4) * TT + 4 * lr;

  __shared__ __align__(16) unsigned short Ksh[2][64][64];
  __shared__ __align__(16) unsigned short Vsh[2][64][64];
  __shared__ __align__(16) unsigned short Plds[4][16][84];

  int rowoff = lane >> 3;            // 0..7 within an 8-row staging segment
  int sslot  = (lane & 7) ^ rowoff;  // pre-swizzled source slot (16B units)

  bf16x8 qf[2];
#pragma unroll
  for (int ks = 0; ks < 2; ++ks)
    qf[ks] = *(const bf16x8*)(Qh + (size_t)(i0 + lr) * HD + ks * 32 + lg * 8);

  f32x4 acc[4];
  float lrun[4] = {0.f, 0.f, 0.f, 0.f};  // per-lane partial of softmax denom
#pragma unroll
  for (int q = 0; q < 4; ++q) acc[q] = (f32x4){0.f, 0.f, 0.f, 0.f};

#define STAGE_KV(BUF, J0)                                                      \
  {                                                                            \
    _Pragma("unroll")                                                          \
    for (int p = 0; p < 2; ++p) {                                              \
      int r0 = wave * 16 + p * 8;                                              \
      gload_lds16(Kh + (size_t)((J0) + r0 + rowoff) * HD + sslot * 8,          \
                  &Ksh[BUF][r0][0]);                                           \
      gload_lds16(Vh + (size_t)(r0 + rowoff) * TT + (J0) + sslot * 8,          \
                  &Vsh[BUF][r0][0]);                                           \
    }                                                                          \
  }

  STAGE_KV(0, 0)
  __syncthreads();

  for (int kt = 0; kt <= g4; ++kt) {
    int cur = kt & 1;
    int j0 = kt * 64;
    if (kt < g4) STAGE_KV(cur ^ 1, j0 + 64)

    // E for current tile (4 x 8B vector loads, swizzled layout)
    ushort4 ev[4];
#pragma unroll
    for (int r = 0; r < 4; ++r)
      ev[r] = *(const ushort4*)(Erow + (size_t)r * TT + j0);

    // ---- QK^T from swizzled LDS ----
    f32x4 s[4];
    __builtin_amdgcn_s_setprio(1);
#pragma unroll
    for (int nj = 0; nj < 4; ++nj) {
      int row = nj * 16 + lr;
      int sw = row & 7;
      bf16x8 k0f = *(const bf16x8*)&Ksh[cur][row][(lg ^ sw) << 3];
      bf16x8 k1f = *(const bf16x8*)&Ksh[cur][row][((4 + lg) ^ sw) << 3];
      f32x4 z = (f32x4){0.f, 0.f, 0.f, 0.f};
      z = __builtin_amdgcn_mfma_f32_16x16x32_bf16(qf[0], k0f, z, 0, 0, 0);
      s[nj] = __builtin_amdgcn_mfma_f32_16x16x32_bf16(qf[1], k1f, z, 0, 0, 0);
    }
    __builtin_amdgcn_s_setprio(0);

    // ---- causal mask (diagonal tile only) ----
    int ibase = i0 + lg * 4;
    if (kt == g4) {
#pragma unroll
      for (int nj = 0; nj < 4; ++nj)
#pragma unroll
        for (int r = 0; r < 4; ++r)
          if (j0 + nj * 16 + lr > ibase + r) s[nj][r] = -1e30f;
    }

    // ---- P = E * exp(s); per-lane partial l; stash bf16 P in LDS ----
#pragma unroll
    for (int r = 0; r < 4; ++r) {
      float p0 = b2f(ev[r].x) * __expf(s[0][r]);
      float p1 = b2f(ev[r].y) * __expf(s[1][r]);
      float p2 = b2f(ev[r].z) * __expf(s[2][r]);
      float p3 = b2f(ev[r].w) * __expf(s[3][r]);
      lrun[r] += (p0 + p1) + (p2 + p3);
      Plds[wave][lg * 4 + r][0 * 16 + lr] = f2b(p0);
      Plds[wave][lg * 4 + r][1 * 16 + lr] = f2b(p1);
      Plds[wave][lg * 4 + r][2 * 16 + lr] = f2b(p2);
      Plds[wave][lg * 4 + r][3 * 16 + lr] = f2b(p3);
    }

    // ---- PV from swizzled LDS ----
    bf16x8 pa0 = *(const bf16x8*)&Plds[wave][lr][lg * 8];
    bf16x8 pa1 = *(const bf16x8*)&Plds[wave][lr][32 + lg * 8];
    __builtin_amdgcn_s_setprio(1);
#pragma unroll
    for (int nd = 0; nd < 4; ++nd) {
      int row = nd * 16 + lr;
      int sw = row & 7;
      bf16x8 v0f = *(const bf16x8*)&Vsh[cur][row][(lg ^ sw) << 3];
      bf16x8 v1f = *(const bf16x8*)&Vsh[cur][row][((4 + lg) ^ sw) << 3];
      acc[nd] = __builtin_amdgcn_mfma_f32_16x16x32_bf16(pa0, v0f, acc[nd], 0, 0, 0);
      acc[nd] = __builtin_amdgcn_mfma_f32_16x16x32_bf16(pa1, v1f, acc[nd], 0, 0, 0);
    }
    __builtin_amdgcn_s_setprio(0);

    __syncthreads();
  }
#undef STAGE_KV

  // ---- epilogue: one l-reduction across the 16 lr lanes, then store ----
#pragma unroll
  for (int r = 0; r < 4; ++r) {
    lrun[r] += __shfl_xor(lrun[r], 1);
    lrun[r] += __shfl_xor(lrun[r], 2);
    lrun[r] += __shfl_xor(lrun[r], 4);
    lrun[r] += __shfl_xor(lrun[r], 8);
    float inv = 1.f / lrun[r];
    int ig = i0 + lg * 4 + r;
    unsigned short* ob = yhb + (size_t)(b * TT + ig) * CC + h * HD;
#pragma unroll
    for (int nd = 0; nd < 4; ++nd)
      ob[nd * 16 + lr] = f2b(acc[nd][r] * inv);
  }
}

// ---------------------------------------------------------------------------
// proj GEMM: y = yhb @ wpT^T + b_proj (128x128 MFMA tile). Grid (32, 6).
// ---------------------------------------------------------------------------
__global__ __launch_bounds__(256, 3) void gemm_proj_bf16(
    const unsigned short* __restrict__ yhb, const unsigned short* __restrict__ wpT,
    const float* __restrict__ b_proj, float* __restrict__ y) {
  __shared__ __align__(16) unsigned short Alds[2][128][32];
  __shared__ __align__(16) unsigned short Blds[2][128][32];
  int mt = blockIdx.x, nt = blockIdx.y;
  int wave = threadIdx.x >> 6, lane = threadIdx.x & 63;
  int lr = lane & 15, lg = lane >> 4;
  int m0 = mt * 128;
  int n0 = nt * 128;

  int srow = lane >> 2;
  int sslot = (lane & 3) ^ (srow & 3);

#define STAGE_AB(BUF, K0)                                                       \
  {                                                                             \
    _Pragma("unroll")                                                           \
    for (int p = 0; p < 2; ++p) {                                               \
      int ar = wave * 32 + p * 16 + srow;                                       \
      gload_lds16(yhb + (size_t)(m0 + ar) * CC + (K0) + (sslot << 3),           \
                  &Alds[BUF][wave * 32 + p * 16][0]);                           \
      gload_lds16(wpT + (size_t)(n0 + ar) * CC + (K0) + (sslot << 3),           \
                  &Blds[BUF][wave * 32 + p * 16][0]);                           \
    }                                                                           \
  }

  f32x4 acc[2][8];
#pragma unroll
  for (int mi = 0; mi < 2; ++mi)
#pragma unroll
    for (int nj = 0; nj < 8; ++nj) acc[mi][nj] = (f32x4){0.f, 0.f, 0.f, 0.f};

  STAGE_AB(0, 0)
  __syncthreads();

  int fslot = lg ^ (lr & 3);
  for (int kt = 0; kt < 24; ++kt) {
    int cur = kt & 1;
    if (kt < 23) STAGE_AB(cur ^ 1, (kt + 1) * 32)
    bf16x8 af[2], bf[8];
#pragma unroll
    for (int mi = 0; mi < 2; ++mi)
      af[mi] = *(const bf16x8*)&Alds[cur][wave * 32 + mi * 16 + lr][fslot << 3];
#pragma unroll
    for (int nj = 0; nj < 8; ++nj)
      bf[nj] = *(const bf16x8*)&Blds[cur][nj * 16 + lr][fslot << 3];
    __builtin_amdgcn_s_setprio(1);
#pragma unroll
    for (int nj = 0; nj < 8; ++nj)
#pragma unroll
      for (int mi = 0; mi < 2; ++mi)
        acc[mi][nj] = __builtin_amdgcn_mfma_f32_16x16x32_bf16(af[mi], bf[nj], acc[mi][nj], 0, 0, 0);
    __builtin_amdgcn_s_setprio(0);
    __syncthreads();
  }
#undef STAGE_AB

  float bias[8];
#pragma unroll
  for (int nj = 0; nj < 8; ++nj) bias[nj] = b_proj[n0 + nj * 16 + lr];
#pragma unroll
  for (int mi = 0; mi < 2; ++mi)
#pragma unroll
    for (int r = 0; r < 4; ++r) {
      int m = m0 + wave * 32 + mi * 16 + lg * 4 + r;
#pragma unroll
      for (int nj = 0; nj < 8; ++nj)
        y[(size_t)m * CC + n0 + nj * 16 + lr] = acc[mi][nj][r] + bias[nj];
    }
}

// ---------------------------------------------------------------------------
extern "C" void kernel_launch(void* const* d_in, const int* in_sizes, int n_in,
                              void* d_out, int out_size, void* d_ws, size_t ws_size,
                              hipStream_t stream) {
  const float* x      = (const float*)d_in[0];
  const float* w_attn = (const float*)d_in[1];
  const float* b_attn = (const float*)d_in[2];
  const float* w_proj = (const float*)d_in[3];
  const float* b_proj = (const float*)d_in[4];

  float* y    = (float*)d_out;          // [B,T,C]
  float* Mreg = y + Y_ELEMS;            // [B,T,T]: S0 (scratch) -> M (final)

  float* ws = (float*)d_ws;
  float* q0       = ws;                               // B*T*64
  float* k0       = q0 + (size_t)BB * TT * HD;
  float* partials = k0 + (size_t)BB * TT * HD;        // B*32*T
  float* ffpart   = partials + (size_t)BB * 32 * TT;  // B*8*T
  unsigned short* xb  = (unsigned short*)(ffpart + (size_t)BB * 8 * TT);  // B*T*C
  unsigned short* wbT = xb + (size_t)Y_ELEMS;                 // 2304*768
  unsigned short* wpT = wbT + (size_t)N3 * CC;                // 768*768
  unsigned short* Qb  = wpT + (size_t)CC * CC;                // B*NH*T*HD
  unsigned short* Kb  = Qb + (size_t)BB * NH * TT * HD;
  unsigned short* Vt  = Kb + (size_t)BB * NH * TT * HD;
  unsigned short* yhb = Vt + (size_t)BB * NH * TT * HD;       // B*T*C
  unsigned short* Eb  = yhb + (size_t)Y_ELEMS;                // B*T*T bf16 (16.8MB)
  // total ws usage ~= 46 MB

  // 1. fused prep: qk0 (long blocks first) + packs + weight transposes
  prep_fused<<<2368, 256, 0, stream>>>(x, w_attn, w_proj, b_attn,
                                       xb, wbT, wpT, q0, k0);
  // 2. fused QKV MFMA GEMM (576 long blocks first) + score0 (short backfill)
  gemm_score_fused<<<2624, 256, 0, stream>>>(
      xb, wbT, b_attn, Qb, Kb, Vt, q0, k0, Mreg, partials);
  // 3. scan: E = exp(-FF) bf16 (jswz) + ffpart row sums; upper-tri early-exit
  scan_write<<<dim3(8, 32, BB), 256, 0, stream>>>(Mreg, partials, Eb, ffpart);
  // 4. fused attention (768 long blocks first) + M writer (backfill stores)
  attn_m_fused<<<1280, 256, 0, stream>>>(Qb, Kb, Vt, Eb, yhb, ffpart, Mreg);
  // 5. proj GEMM (128x128)
  gemm_proj_bf16<<<dim3(32, 6), 256, 0, stream>>>(yhb, wpT, b_proj, y);
}